// Round 1
// baseline (1200.988 us; speedup 1.0000x reference)
//
#include <hip/hip_runtime.h>

#define N_NODES 4096
#define N_EDGES 262144
#define EPS 1e-5f

// workspace offsets (floats)
#define O_Q      0
#define O_K      524288
#define O_V      1048576
#define O_CTX    1572864
#define O_BASE   2097152
#define O_UPD    2621440
#define O_NCTX   3145728
#define O_XSA    3407872
#define O_XTB    3670016

// ---------------- K1: xp = x@inp_w.T+b ; q,k,v projections (fused, per node) ----------------
__global__ __launch_bounds__(128) void k_proj_qkv(
    const float* __restrict__ x, const float* __restrict__ inp_w, const float* __restrict__ inp_b,
    const float* __restrict__ wq, const float* __restrict__ bq,
    const float* __restrict__ wk, const float* __restrict__ bk,
    const float* __restrict__ wv, const float* __restrict__ bv,
    float* __restrict__ q, float* __restrict__ k, float* __restrict__ v)
{
    __shared__ float xs[128];
    __shared__ float xps[128];
    int n = blockIdx.x;
    int c = threadIdx.x;
    xs[c] = x[n*128 + c];
    __syncthreads();
    float acc = inp_b[c];
    const float* wrow = inp_w + c*128;
    #pragma unroll 8
    for (int i = 0; i < 128; i++) acc += xs[i] * wrow[i];
    xps[c] = acc;
    __syncthreads();
    float aq = bq[c], ak = bk[c], av = bv[c];
    const float* qrow = wq + c*128;
    const float* krow = wk + c*128;
    const float* vrow = wv + c*128;
    #pragma unroll 4
    for (int i = 0; i < 128; i++) {
        float xv = xps[i];
        aq += xv * qrow[i];
        ak += xv * krow[i];
        av += xv * vrow[i];
    }
    q[n*128+c] = aq; k[n*128+c] = ak; v[n*128+c] = av;
}

// ---------------- K2: dense attention, online softmax, 8-way key split ----------------
// block = 256 threads: split = tid&7, p = tid>>3 (32 pairs: q_local = p&7, head = p>>3)
// grid = 4096/8 = 512 blocks. K/V tiles of 32 keys x 128 ch in LDS, row stride 132 (pad).
__global__ __launch_bounds__(256) void k_attn(
    const float* __restrict__ q, const float* __restrict__ k, const float* __restrict__ v,
    float* __restrict__ ctx)
{
    __shared__ float klds[32*132];
    __shared__ float vlds[32*132];
    int tid = threadIdx.x;
    int split = tid & 7;
    int p = tid >> 3;
    int ql = p & 7;
    int h = p >> 3;
    int qn = blockIdx.x * 8 + ql;
    float qreg[32];
    const float* qp = q + qn*128 + h*32;
    #pragma unroll
    for (int d = 0; d < 32; d++) qreg[d] = qp[d];
    float m_run = -1e30f, l_run = 0.f;
    float cacc[32];
    #pragma unroll
    for (int d = 0; d < 32; d++) cacc[d] = 0.f;
    const float scale = 0.17677669529663687f; // 1/sqrt(32)
    for (int tile = 0; tile < N_NODES; tile += 32) {
        __syncthreads();
        for (int i = tid; i < 32*32; i += 256) {  // 1024 float4 pairs
            int row = i >> 5, c4 = i & 31;
            float4 kv4 = *(const float4*)(k + (tile+row)*128 + c4*4);
            float4 vv4 = *(const float4*)(v + (tile+row)*128 + c4*4);
            *(float4*)(klds + row*132 + c4*4) = kv4;
            *(float4*)(vlds + row*132 + c4*4) = vv4;
        }
        __syncthreads();
        #pragma unroll
        for (int kk = 0; kk < 4; kk++) {
            int key = split*4 + kk;
            const float* kr = klds + key*132 + h*32;
            float s = 0.f;
            #pragma unroll
            for (int d = 0; d < 32; d++) s += qreg[d]*kr[d];
            s *= scale;
            if (s > m_run) {
                float sc = __expf(m_run - s);
                l_run *= sc;
                #pragma unroll
                for (int d = 0; d < 32; d++) cacc[d] *= sc;
                m_run = s;
            }
            float pv = __expf(s - m_run);
            l_run += pv;
            const float* vr = vlds + key*132 + h*32;
            #pragma unroll
            for (int d = 0; d < 32; d++) cacc[d] += pv * vr[d];
        }
    }
    // merge the 8 splits (lane bits 0..2) via butterfly
    #pragma unroll
    for (int mask = 1; mask < 8; mask <<= 1) {
        float m2 = __shfl_xor(m_run, mask, 64);
        float l2 = __shfl_xor(l_run, mask, 64);
        float mn = fmaxf(m_run, m2);
        float s1 = __expf(m_run - mn);
        float s2 = __expf(m2 - mn);
        l_run = l_run*s1 + l2*s2;
        #pragma unroll
        for (int d = 0; d < 32; d++) {
            float c2 = __shfl_xor(cacc[d], mask, 64);
            cacc[d] = cacc[d]*s1 + c2*s2;
        }
        m_run = mn;
    }
    float inv = 1.f / l_run;
    if (split == 0) {
        float* cp = ctx + qn*128 + h*32;
        #pragma unroll
        for (int d = 0; d < 32; d++) cp[d] = cacc[d]*inv;
    }
}

// ---------------- K3: attn_out + outp (fused, per node) ----------------
__global__ __launch_bounds__(128) void k_out_base(
    const float* __restrict__ ctx, const float* __restrict__ aw, const float* __restrict__ ab,
    const float* __restrict__ ow, const float* __restrict__ ob, float* __restrict__ base)
{
    __shared__ float cs[128];
    __shared__ float as[128];
    int n = blockIdx.x, c = threadIdx.x;
    cs[c] = ctx[n*128+c];
    __syncthreads();
    float acc = ab[c];
    const float* wr = aw + c*128;
    #pragma unroll 8
    for (int i = 0; i < 128; i++) acc += cs[i]*wr[i];
    as[c] = acc;
    __syncthreads();
    float acc2 = ob[c];
    const float* wr2 = ow + c*128;
    #pragma unroll 8
    for (int i = 0; i < 128; i++) acc2 += as[i]*wr2[i];
    base[n*128+c] = acc2;
}

// ---------------- K6a: per-node precompute of sc-MLP x_src / x_tgt partials ----------------
__global__ __launch_bounds__(128) void k_node_sc(
    const float* __restrict__ x, const float* __restrict__ sc_w1,
    float* __restrict__ xsa, float* __restrict__ xtb)
{
    __shared__ float xs[128];
    int n = blockIdx.x, c = threadIdx.x;
    xs[c] = x[n*128+c];
    __syncthreads();
    int r = c & 63;
    const float* wr = sc_w1 + r*320 + ((c >= 64) ? 128 : 0);
    float acc = 0.f;
    #pragma unroll 8
    for (int i = 0; i < 128; i++) acc += xs[i]*wr[i];
    if (c < 64) xsa[n*64+r] = acc; else xtb[n*64+r] = acc;
}

// ---------------- K6b: fused temporal MLP + LN + sc-MLP + sigmoid + node_ctx scatter ----------------
// one wave per edge, 4 edges per 256-thread block, grid-stride
__global__ __launch_bounds__(256) void k_edge(
    const int* __restrict__ eidx, const float* __restrict__ etime,
    const float* __restrict__ te_w1, const float* __restrict__ te_b1,
    const float* __restrict__ te_w2, const float* __restrict__ te_b2,
    const float* __restrict__ ln_g, const float* __restrict__ ln_b,
    const float* __restrict__ sc_b1, const float* __restrict__ sc_w1,
    const float* __restrict__ sc_w2, const float* __restrict__ sc_b2,
    const float* __restrict__ decay_p,
    const float* __restrict__ xsa, const float* __restrict__ xtb,
    float* __restrict__ nctx)
{
    __shared__ float w2T[32*64];   // te_w2 transposed: [j][c]
    __shared__ float WcT[64*64];   // sc_w1[:,256+j] transposed: [j][r]
    __shared__ float cw1[32], cb1[32], cb2[64], cg[64], cb[64], csb1[64], csw2[64];
    __shared__ float tfb[4][64];
    int tid = threadIdx.x;
    for (int i = tid; i < 32*64; i += 256) { int j = i >> 6, c = i & 63; w2T[i] = te_w2[c*32 + j]; }
    for (int i = tid; i < 64*64; i += 256) { int j = i >> 6, r = i & 63; WcT[i] = sc_w1[r*320 + 256 + j]; }
    if (tid < 32) { cw1[tid] = te_w1[tid]; cb1[tid] = te_b1[tid]; }
    if (tid < 64) { cb2[tid]=te_b2[tid]; cg[tid]=ln_g[tid]; cb[tid]=ln_b[tid];
                    csb1[tid]=sc_b1[tid]; csw2[tid]=sc_w2[tid]; }
    __syncthreads();
    float decay = decay_p[0];
    float sb2 = sc_b2[0];
    int lane = tid & 63;
    int slot = tid >> 6;
    int nblocks = gridDim.x;
    for (int eg = blockIdx.x; eg*4 < N_EDGES; eg += nblocks) {
        int e = eg*4 + slot;
        int src = eidx[e];
        int tgt = eidx[N_EDGES + e];
        float t = etime[e];
        float wt = t * __expf(-fabsf(t)*decay);
        float acc = cb2[lane];
        #pragma unroll 8
        for (int j = 0; j < 32; j++) {
            float hj = fmaxf(0.f, wt*cw1[j] + cb1[j]);
            acc += hj * w2T[j*64 + lane];
        }
        // LayerNorm across the 64 lanes (= 64 channels)
        float s = acc;
        #pragma unroll
        for (int m = 32; m >= 1; m >>= 1) s += __shfl_xor(s, m, 64);
        float mu = s * (1.f/64.f);
        float d = acc - mu;
        float s2 = d*d;
        #pragma unroll
        for (int m = 32; m >= 1; m >>= 1) s2 += __shfl_xor(s2, m, 64);
        float tf = d * rsqrtf(s2*(1.f/64.f) + EPS) * cg[lane] + cb[lane];
        __syncthreads();
        tfb[slot][lane] = tf;
        __syncthreads();
        float rh = csb1[lane] + xsa[src*64 + lane] + xtb[tgt*64 + lane];
        #pragma unroll 8
        for (int j = 0; j < 64; j++) rh += tfb[slot][j] * WcT[j*64 + lane];
        rh = fmaxf(rh, 0.f);
        float ps = rh * csw2[lane];
        #pragma unroll
        for (int m = 32; m >= 1; m >>= 1) ps += __shfl_xor(ps, m, 64);
        float score = 1.f / (1.f + __expf(-(ps + sb2)));
        atomicAdd(&nctx[src*64 + lane], tf * score);
    }
}

// ---------------- K5: edge-weighted scatter of base into upd ----------------
__global__ __launch_bounds__(256) void k_scatter(
    const int* __restrict__ eidx, const float* __restrict__ eattr,
    const float* __restrict__ base, float* __restrict__ upd)
{
    int tid = threadIdx.x;
    int e = blockIdx.x*2 + (tid >> 7);
    int c = tid & 127;
    float hier = eattr[e*17 + 16];
    if (hier > 0.f) {
        float tfj = eattr[e*17 + 5];
        int src = eidx[e], tgt = eidx[N_EDGES + e];
        float sig = 1.f/(1.f + __expf(-tfj));
        float wf = hier * sig * 0.3f;
        float wr = hier * 0.1f;
        atomicAdd(&upd[src*128 + c], base[tgt*128 + c] * wf);
        atomicAdd(&upd[tgt*128 + c], base[src*128 + c] * wr);
    }
}

// ---------------- K7: agg GEMM + LayerNorm + relu (per node) ----------------
__global__ __launch_bounds__(256) void k_final(
    const float* __restrict__ base, const float* __restrict__ upd, const float* __restrict__ nctx,
    const float* __restrict__ agg_w, const float* __restrict__ agg_b,
    const float* __restrict__ g, const float* __restrict__ b, float* __restrict__ out)
{
    __shared__ float comb[192];
    __shared__ float red[8];
    int n = blockIdx.x, c = threadIdx.x;
    if (c < 128) comb[c] = base[n*128+c] + upd[n*128+c];
    else if (c < 192) comb[c] = nctx[n*64 + (c-128)];
    __syncthreads();
    float acc = agg_b[c];
    const float* wr = agg_w + c*192;
    #pragma unroll 4
    for (int i = 0; i < 192; i++) acc += comb[i]*wr[i];
    int lane = c & 63, w = c >> 6;
    float s = acc;
    #pragma unroll
    for (int m = 32; m >= 1; m >>= 1) s += __shfl_xor(s, m, 64);
    if (lane == 0) red[w] = s;
    __syncthreads();
    float mu = (red[0]+red[1]+red[2]+red[3]) * (1.f/256.f);
    float d = acc - mu;
    float s2 = d*d;
    #pragma unroll
    for (int m = 32; m >= 1; m >>= 1) s2 += __shfl_xor(s2, m, 64);
    if (lane == 0) red[4+w] = s2;
    __syncthreads();
    float var = (red[4]+red[5]+red[6]+red[7]) * (1.f/256.f);
    float y = d * rsqrtf(var + EPS) * g[c] + b[c];
    out[n*256+c] = fmaxf(y, 0.f);
}

extern "C" void kernel_launch(void* const* d_in, const int* in_sizes, int n_in,
                              void* d_out, int out_size, void* d_ws, size_t ws_size,
                              hipStream_t stream)
{
    const float* x        = (const float*)d_in[0];
    const int*   eidx     = (const int*)d_in[1];
    const float* etime    = (const float*)d_in[2];
    const float* eattr    = (const float*)d_in[3];
    const float* te_w1    = (const float*)d_in[4];
    const float* te_b1    = (const float*)d_in[5];
    const float* te_w2    = (const float*)d_in[6];
    const float* te_b2    = (const float*)d_in[7];
    const float* te_ln_g  = (const float*)d_in[8];
    const float* te_ln_b  = (const float*)d_in[9];
    const float* inp_w    = (const float*)d_in[10];
    const float* inp_b    = (const float*)d_in[11];
    const float* wq       = (const float*)d_in[12];
    const float* bq       = (const float*)d_in[13];
    const float* wk       = (const float*)d_in[14];
    const float* bk       = (const float*)d_in[15];
    const float* wv       = (const float*)d_in[16];
    const float* bv       = (const float*)d_in[17];
    const float* aow      = (const float*)d_in[18];
    const float* aob      = (const float*)d_in[19];
    const float* ow       = (const float*)d_in[20];
    const float* ob       = (const float*)d_in[21];
    const float* sc_w1    = (const float*)d_in[22];
    const float* sc_b1    = (const float*)d_in[23];
    const float* sc_w2    = (const float*)d_in[24];
    const float* sc_b2    = (const float*)d_in[25];
    const float* agg_w    = (const float*)d_in[26];
    const float* agg_b    = (const float*)d_in[27];
    const float* agg_g    = (const float*)d_in[28];
    const float* agg_bb   = (const float*)d_in[29];
    const float* decay    = (const float*)d_in[30];
    float* ws = (float*)d_ws;
    float* out = (float*)d_out;

    // zero upd (524288) + node_ctx (262144) — contiguous
    hipMemsetAsync(ws + O_UPD, 0, (524288 + 262144)*sizeof(float), stream);

    k_proj_qkv<<<N_NODES, 128, 0, stream>>>(x, inp_w, inp_b, wq, bq, wk, bk, wv, bv,
                                            ws+O_Q, ws+O_K, ws+O_V);
    k_node_sc<<<N_NODES, 128, 0, stream>>>(x, sc_w1, ws+O_XSA, ws+O_XTB);
    k_edge<<<2048, 256, 0, stream>>>(eidx, etime, te_w1, te_b1, te_w2, te_b2,
                                     te_ln_g, te_ln_b, sc_b1, sc_w1, sc_w2, sc_b2,
                                     decay, ws+O_XSA, ws+O_XTB, ws+O_NCTX);
    k_attn<<<N_NODES/8, 256, 0, stream>>>(ws+O_Q, ws+O_K, ws+O_V, ws+O_CTX);
    k_out_base<<<N_NODES, 128, 0, stream>>>(ws+O_CTX, aow, aob, ow, ob, ws+O_BASE);
    k_scatter<<<N_EDGES/2, 256, 0, stream>>>(eidx, eattr, ws+O_BASE, ws+O_UPD);
    k_final<<<N_NODES, 256, 0, stream>>>(ws+O_BASE, ws+O_UPD, ws+O_NCTX,
                                         agg_w, agg_b, agg_g, agg_bb, out);
}

// Round 2
// 1068.726 us; speedup vs baseline: 1.1238x; 1.1238x over previous
//
#include <hip/hip_runtime.h>

#define N_NODES 4096
#define N_EDGES 262144
#define EPS 1e-5f

// workspace offsets (float units)
#define O_CTXT 0        // ctx^T f32 [128][4096]
#define O_BASE 524288   // base [4096][128]
#define O_UPD  1048576  // upd  [4096][128]
#define O_NCTX 1572864  // nctx [4096][64]
#define O_XSA  1835008
#define O_XTB  2097152
#define O_QB   2359296  // bf16 [4][4096][32] (scaled by log2e/sqrt(d))
#define O_KB   2621440  // bf16 [4][4096][32]
#define O_VT   2883584  // bf16 [4][32][4096]  (V transposed)

typedef __attribute__((ext_vector_type(8))) short short8v;
typedef __attribute__((ext_vector_type(4))) float f32x4;

__device__ __forceinline__ ushort f2bf(float x) {
    uint u = __builtin_bit_cast(uint, x);
    uint r = (u + 0x7FFFu + ((u >> 16) & 1u)) >> 16;
    return (ushort)r;
}
__device__ __forceinline__ float fexp2(float x) { return __builtin_amdgcn_exp2f(x); }

// ---------------- K1: xp = x@inp_w.T+b ; q,k,v projections -> bf16 qb,kb,vt ----------------
__global__ __launch_bounds__(128) void k_proj_qkv(
    const float* __restrict__ x, const float* __restrict__ inp_w, const float* __restrict__ inp_b,
    const float* __restrict__ wq, const float* __restrict__ bq,
    const float* __restrict__ wk, const float* __restrict__ bk,
    const float* __restrict__ wv, const float* __restrict__ bv,
    ushort* __restrict__ qb, ushort* __restrict__ kbuf, ushort* __restrict__ vt)
{
    __shared__ float xs[128];
    __shared__ float xps[128];
    int n = blockIdx.x;
    int c = threadIdx.x;
    xs[c] = x[n*128 + c];
    __syncthreads();
    float acc = inp_b[c];
    const float* wrow = inp_w + c*128;
    #pragma unroll 8
    for (int i = 0; i < 128; i++) acc += xs[i] * wrow[i];
    xps[c] = acc;
    __syncthreads();
    float aq = bq[c], ak = bk[c], av = bv[c];
    const float* qrow = wq + c*128;
    const float* krow = wk + c*128;
    const float* vrow = wv + c*128;
    #pragma unroll 4
    for (int i = 0; i < 128; i++) {
        float xv = xps[i];
        aq += xv * qrow[i];
        ak += xv * krow[i];
        av += xv * vrow[i];
    }
    const float QSCALE = 0.17677669529663687f * 1.4426950408889634f; // 1/sqrt(32) * log2(e)
    int h = c >> 5, d = c & 31;
    int qi = h*131072 + n*32 + d;
    qb[qi]   = f2bf(aq * QSCALE);
    kbuf[qi] = f2bf(ak);
    vt[c*4096 + n] = f2bf(av);   // vt[(h*32+d)][n]
}

// ---------------- K2: MFMA flash attention ----------------
// grid = 1024: blockIdx -> (qt = bx>>2, h = bx&3). 4 waves split keys 4x1024.
// S^T = mfma(K_tile, Q^T): lane holds q = l&15, keys = permuted rows.
// A-row r of QK maps to key 8*(r>>2)+(r&3) (+4 for second mfma), so that the
// per-lane P values land exactly in the PV B-fragment order (keys g*8+0..7).
__global__ __launch_bounds__(256) void k_attn(
    const ushort* __restrict__ qb, const ushort* __restrict__ kb,
    const ushort* __restrict__ vt, float* __restrict__ ctxT)
{
    __shared__ float mbuf[4][16];
    __shared__ float lbuf[4][16];
    __shared__ float obuf[4][512];
    int tid = threadIdx.x;
    int lane = tid & 63;
    int wv = tid >> 6;
    int h = blockIdx.x & 3;
    int qt = blockIdx.x >> 2;
    int q15 = lane & 15;
    int g = lane >> 4;
    const ushort* qhb = qb + h*131072;
    const ushort* khb = kb + h*131072;
    const ushort* vhb = vt + h*131072;
    short8v qf = *(const short8v*)(qhb + (qt*16 + q15)*32 + g*8);
    int key0off = ((q15 >> 2) << 3) + (q15 & 3);   // permuted key for A-row (l&15)
    f32x4 o0 = {0.f,0.f,0.f,0.f}, o1 = {0.f,0.f,0.f,0.f};
    const f32x4 z = {0.f,0.f,0.f,0.f};
    float m_run = -1e30f, l_run = 0.f;
    int kstart = wv * 1024;
    for (int k32 = kstart; k32 < kstart + 1024; k32 += 32) {
        short8v kf0 = *(const short8v*)(khb + (k32 + key0off)*32 + g*8);
        short8v kf1 = *(const short8v*)(khb + (k32 + key0off + 4)*32 + g*8);
        short8v vf0 = *(const short8v*)(vhb + q15*4096 + k32 + g*8);
        short8v vf1 = *(const short8v*)(vhb + (16 + q15)*4096 + k32 + g*8);
        f32x4 s0 = __builtin_amdgcn_mfma_f32_16x16x32_bf16(kf0, qf, z, 0, 0, 0);
        f32x4 s1 = __builtin_amdgcn_mfma_f32_16x16x32_bf16(kf1, qf, z, 0, 0, 0);
        float tmax = fmaxf(fmaxf(fmaxf(s0[0], s0[1]), fmaxf(s0[2], s0[3])),
                           fmaxf(fmaxf(s1[0], s1[1]), fmaxf(s1[2], s1[3])));
        tmax = fmaxf(tmax, __shfl_xor(tmax, 16, 64));
        tmax = fmaxf(tmax, __shfl_xor(tmax, 32, 64));
        float mnew = fmaxf(m_run, tmax);
        float sc = fexp2(m_run - mnew);
        float p0 = fexp2(s0[0] - mnew), p1 = fexp2(s0[1] - mnew);
        float p2 = fexp2(s0[2] - mnew), p3 = fexp2(s0[3] - mnew);
        float p4 = fexp2(s1[0] - mnew), p5 = fexp2(s1[1] - mnew);
        float p6 = fexp2(s1[2] - mnew), p7 = fexp2(s1[3] - mnew);
        float psum = ((p0 + p1) + (p2 + p3)) + ((p4 + p5) + (p6 + p7));
        psum += __shfl_xor(psum, 16, 64);
        psum += __shfl_xor(psum, 32, 64);
        l_run = l_run * sc + psum;
        m_run = mnew;
        #pragma unroll
        for (int r = 0; r < 4; r++) { o0[r] *= sc; o1[r] *= sc; }
        short8v pf;
        pf[0] = (short)f2bf(p0); pf[1] = (short)f2bf(p1);
        pf[2] = (short)f2bf(p2); pf[3] = (short)f2bf(p3);
        pf[4] = (short)f2bf(p4); pf[5] = (short)f2bf(p5);
        pf[6] = (short)f2bf(p6); pf[7] = (short)f2bf(p7);
        o0 = __builtin_amdgcn_mfma_f32_16x16x32_bf16(vf0, pf, o0, 0, 0, 0);
        o1 = __builtin_amdgcn_mfma_f32_16x16x32_bf16(vf1, pf, o1, 0, 0, 0);
    }
    if (lane < 16) { mbuf[wv][lane] = m_run; lbuf[wv][lane] = l_run; }
    #pragma unroll
    for (int r = 0; r < 4; r++) {
        obuf[wv][r*64 + lane]       = o0[r];
        obuf[wv][(4 + r)*64 + lane] = o1[r];
    }
    __syncthreads();
    // merge the 4 key-splits; 512 O^T elements, 2 per thread
    for (int e = tid; e < 512; e += 256) {
        int lp = e & 63, r8 = e >> 6;
        int q = lp & 15;
        float m0 = mbuf[0][q], m1 = mbuf[1][q], m2 = mbuf[2][q], m3 = mbuf[3][q];
        float M = fmaxf(fmaxf(m0, m1), fmaxf(m2, m3));
        float sc0 = fexp2(m0 - M), sc1 = fexp2(m1 - M);
        float sc2 = fexp2(m2 - M), sc3 = fexp2(m3 - M);
        float L = lbuf[0][q]*sc0 + lbuf[1][q]*sc1 + lbuf[2][q]*sc2 + lbuf[3][q]*sc3;
        float a = obuf[0][e]*sc0 + obuf[1][e]*sc1 + obuf[2][e]*sc2 + obuf[3][e]*sc3;
        int d = ((lp >> 4) << 2) + (r8 & 3) + ((r8 >> 2) << 4);
        ctxT[(h*32 + d)*4096 + qt*16 + q] = a / L;
    }
}

// ---------------- K3: attn_out + outp (fused, per node) ----------------
__global__ __launch_bounds__(128) void k_out_base(
    const float* __restrict__ ctxT, const float* __restrict__ aw, const float* __restrict__ ab,
    const float* __restrict__ ow, const float* __restrict__ ob, float* __restrict__ base)
{
    __shared__ float cs[128];
    __shared__ float as[128];
    int n = blockIdx.x, c = threadIdx.x;
    cs[c] = ctxT[c*4096 + n];
    __syncthreads();
    float acc = ab[c];
    const float* wr = aw + c*128;
    #pragma unroll 8
    for (int i = 0; i < 128; i++) acc += cs[i]*wr[i];
    as[c] = acc;
    __syncthreads();
    float acc2 = ob[c];
    const float* wr2 = ow + c*128;
    #pragma unroll 8
    for (int i = 0; i < 128; i++) acc2 += as[i]*wr2[i];
    base[n*128+c] = acc2;
}

// ---------------- K6a: per-node precompute of sc-MLP x_src / x_tgt partials ----------------
__global__ __launch_bounds__(128) void k_node_sc(
    const float* __restrict__ x, const float* __restrict__ sc_w1,
    float* __restrict__ xsa, float* __restrict__ xtb)
{
    __shared__ float xs[128];
    int n = blockIdx.x, c = threadIdx.x;
    xs[c] = x[n*128+c];
    __syncthreads();
    int r = c & 63;
    const float* wr = sc_w1 + r*320 + ((c >= 64) ? 128 : 0);
    float acc = 0.f;
    #pragma unroll 8
    for (int i = 0; i < 128; i++) acc += xs[i]*wr[i];
    if (c < 64) xsa[n*64+r] = acc; else xtb[n*64+r] = acc;
}

// ---------------- K6b: fused temporal MLP + LN + sc-MLP + sigmoid + node_ctx scatter ----------------
__global__ __launch_bounds__(256) void k_edge(
    const int* __restrict__ eidx, const float* __restrict__ etime,
    const float* __restrict__ te_w1, const float* __restrict__ te_b1,
    const float* __restrict__ te_w2, const float* __restrict__ te_b2,
    const float* __restrict__ ln_g, const float* __restrict__ ln_b,
    const float* __restrict__ sc_b1, const float* __restrict__ sc_w1,
    const float* __restrict__ sc_w2, const float* __restrict__ sc_b2,
    const float* __restrict__ decay_p,
    const float* __restrict__ xsa, const float* __restrict__ xtb,
    float* __restrict__ nctx)
{
    __shared__ float w2T[32*64];   // te_w2 transposed: [j][c]
    __shared__ float WcT[64*64];   // sc_w1[:,256+j] transposed: [j][r]
    __shared__ float cw1[32], cb1[32], cb2[64], cg[64], cb[64], csb1[64], csw2[64];
    int tid = threadIdx.x;
    for (int i = tid; i < 32*64; i += 256) { int j = i >> 6, c = i & 63; w2T[i] = te_w2[c*32 + j]; }
    for (int i = tid; i < 64*64; i += 256) { int j = i >> 6, r = i & 63; WcT[i] = sc_w1[r*320 + 256 + j]; }
    if (tid < 32) { cw1[tid] = te_w1[tid]; cb1[tid] = te_b1[tid]; }
    if (tid < 64) { cb2[tid]=te_b2[tid]; cg[tid]=ln_g[tid]; cb[tid]=ln_b[tid];
                    csb1[tid]=sc_b1[tid]; csw2[tid]=sc_w2[tid]; }
    __syncthreads();
    float decay = decay_p[0];
    float sb2 = sc_b2[0];
    int lane = tid & 63;
    int slot = tid >> 6;
    int nblocks = gridDim.x;
    for (int eg = blockIdx.x; eg*4 < N_EDGES; eg += nblocks) {
        int e = eg*4 + slot;
        int src = eidx[e];
        int tgt = eidx[N_EDGES + e];
        float t = etime[e];
        float wt = t * __expf(-fabsf(t)*decay);
        float acc = cb2[lane];
        #pragma unroll 8
        for (int j = 0; j < 32; j++) {
            float hj = fmaxf(0.f, wt*cw1[j] + cb1[j]);
            acc += hj * w2T[j*64 + lane];
        }
        // LayerNorm across the 64 lanes (= 64 channels)
        float s = acc;
        #pragma unroll
        for (int m = 32; m >= 1; m >>= 1) s += __shfl_xor(s, m, 64);
        float mu = s * (1.f/64.f);
        float d = acc - mu;
        float s2 = d*d;
        #pragma unroll
        for (int m = 32; m >= 1; m >>= 1) s2 += __shfl_xor(s2, m, 64);
        float tf = d * rsqrtf(s2*(1.f/64.f) + EPS) * cg[lane] + cb[lane];
        float rh = csb1[lane] + xsa[src*64 + lane] + xtb[tgt*64 + lane];
        #pragma unroll
        for (int j = 0; j < 64; j++) rh += __shfl(tf, j, 64) * WcT[j*64 + lane];
        rh = fmaxf(rh, 0.f);
        float ps = rh * csw2[lane];
        #pragma unroll
        for (int m = 32; m >= 1; m >>= 1) ps += __shfl_xor(ps, m, 64);
        float score = 1.f / (1.f + __expf(-(ps + sb2)));
        atomicAdd(&nctx[src*64 + lane], tf * score);
    }
}

// ---------------- K5: edge-weighted scatter of base into upd (wave per edge) ----------------
__global__ __launch_bounds__(256) void k_scatter(
    const int* __restrict__ eidx, const float* __restrict__ eattr,
    const float* __restrict__ base, float* __restrict__ upd)
{
    int lane = threadIdx.x & 63;
    int wv = threadIdx.x >> 6;
    for (int e = blockIdx.x*4 + wv; e < N_EDGES; e += 2048*4) {
        float hier = eattr[e*17 + 16];
        if (hier > 0.f) {
            float tfj = eattr[e*17 + 5];
            int src = eidx[e], tgt = eidx[N_EDGES + e];
            float sig = 1.f/(1.f + __expf(-tfj));
            float wf = hier * sig * 0.3f;
            float wr = hier * 0.1f;
            float2 bt = *(const float2*)(base + tgt*128 + lane*2);
            float2 bs = *(const float2*)(base + src*128 + lane*2);
            atomicAdd(&upd[src*128 + lane*2],     bt.x * wf);
            atomicAdd(&upd[src*128 + lane*2 + 1], bt.y * wf);
            atomicAdd(&upd[tgt*128 + lane*2],     bs.x * wr);
            atomicAdd(&upd[tgt*128 + lane*2 + 1], bs.y * wr);
        }
    }
}

// ---------------- K7: agg GEMM + LayerNorm + relu (per node) ----------------
__global__ __launch_bounds__(256) void k_final(
    const float* __restrict__ base, const float* __restrict__ upd, const float* __restrict__ nctx,
    const float* __restrict__ agg_w, const float* __restrict__ agg_b,
    const float* __restrict__ g, const float* __restrict__ b, float* __restrict__ out)
{
    __shared__ float comb[192];
    __shared__ float red[8];
    int n = blockIdx.x, c = threadIdx.x;
    if (c < 128) comb[c] = base[n*128+c] + upd[n*128+c];
    else if (c < 192) comb[c] = nctx[n*64 + (c-128)];
    __syncthreads();
    float acc = agg_b[c];
    const float* wr = agg_w + c*192;
    #pragma unroll 4
    for (int i = 0; i < 192; i++) acc += comb[i]*wr[i];
    int lane = c & 63, w = c >> 6;
    float s = acc;
    #pragma unroll
    for (int m = 32; m >= 1; m >>= 1) s += __shfl_xor(s, m, 64);
    if (lane == 0) red[w] = s;
    __syncthreads();
    float mu = (red[0]+red[1]+red[2]+red[3]) * (1.f/256.f);
    float d = acc - mu;
    float s2 = d*d;
    #pragma unroll
    for (int m = 32; m >= 1; m >>= 1) s2 += __shfl_xor(s2, m, 64);
    if (lane == 0) red[4+w] = s2;
    __syncthreads();
    float var = (red[4]+red[5]+red[6]+red[7]) * (1.f/256.f);
    float y = d * rsqrtf(var + EPS) * g[c] + b[c];
    out[n*256+c] = fmaxf(y, 0.f);
}

extern "C" void kernel_launch(void* const* d_in, const int* in_sizes, int n_in,
                              void* d_out, int out_size, void* d_ws, size_t ws_size,
                              hipStream_t stream)
{
    const float* x        = (const float*)d_in[0];
    const int*   eidx     = (const int*)d_in[1];
    const float* etime    = (const float*)d_in[2];
    const float* eattr    = (const float*)d_in[3];
    const float* te_w1    = (const float*)d_in[4];
    const float* te_b1    = (const float*)d_in[5];
    const float* te_w2    = (const float*)d_in[6];
    const float* te_b2    = (const float*)d_in[7];
    const float* te_ln_g  = (const float*)d_in[8];
    const float* te_ln_b  = (const float*)d_in[9];
    const float* inp_w    = (const float*)d_in[10];
    const float* inp_b    = (const float*)d_in[11];
    const float* wq       = (const float*)d_in[12];
    const float* bq       = (const float*)d_in[13];
    const float* wk       = (const float*)d_in[14];
    const float* bk       = (const float*)d_in[15];
    const float* wv       = (const float*)d_in[16];
    const float* bv       = (const float*)d_in[17];
    const float* aow      = (const float*)d_in[18];
    const float* aob      = (const float*)d_in[19];
    const float* ow       = (const float*)d_in[20];
    const float* ob       = (const float*)d_in[21];
    const float* sc_w1    = (const float*)d_in[22];
    const float* sc_b1    = (const float*)d_in[23];
    const float* sc_w2    = (const float*)d_in[24];
    const float* sc_b2    = (const float*)d_in[25];
    const float* agg_w    = (const float*)d_in[26];
    const float* agg_b    = (const float*)d_in[27];
    const float* agg_g    = (const float*)d_in[28];
    const float* agg_bb   = (const float*)d_in[29];
    const float* decay    = (const float*)d_in[30];
    float* ws = (float*)d_ws;
    float* out = (float*)d_out;
    ushort* qb   = (ushort*)(ws + O_QB);
    ushort* kbuf = (ushort*)(ws + O_KB);
    ushort* vt   = (ushort*)(ws + O_VT);

    // zero upd + nctx (contiguous)
    hipMemsetAsync(ws + O_UPD, 0, (524288 + 262144)*sizeof(float), stream);

    k_proj_qkv<<<N_NODES, 128, 0, stream>>>(x, inp_w, inp_b, wq, bq, wk, bk, wv, bv,
                                            qb, kbuf, vt);
    k_node_sc<<<N_NODES, 128, 0, stream>>>(x, sc_w1, ws+O_XSA, ws+O_XTB);
    k_edge<<<2048, 256, 0, stream>>>(eidx, etime, te_w1, te_b1, te_w2, te_b2,
                                     te_ln_g, te_ln_b, sc_b1, sc_w1, sc_w2, sc_b2,
                                     decay, ws+O_XSA, ws+O_XTB, ws+O_NCTX);
    k_attn<<<1024, 256, 0, stream>>>(qb, kbuf, vt, ws+O_CTXT);
    k_out_base<<<N_NODES, 128, 0, stream>>>(ws+O_CTXT, aow, aob, ow, ob, ws+O_BASE);
    k_scatter<<<2048, 256, 0, stream>>>(eidx, eattr, ws+O_BASE, ws+O_UPD);
    k_final<<<N_NODES, 256, 0, stream>>>(ws+O_BASE, ws+O_UPD, ws+O_NCTX,
                                         agg_w, agg_b, agg_g, agg_bb, out);
}

// Round 3
// 680.475 us; speedup vs baseline: 1.7649x; 1.5706x over previous
//
#include <hip/hip_runtime.h>
#include <hip/hip_fp16.h>

#define N_NODES 4096
#define N_EDGES 262144
#define EPS 1e-5f
#define CAP 192

// workspace offsets (float units)
#define O_CTXT 0        // ctx^T f32 [128][4096]
#define O_BASE 524288   // base [4096][128]
#define O_XSA  1048576
#define O_XTB  1310720
#define O_TAB  1572864  // 33 regions x 320: [AG 64][BG 64][P 64][Q 64][qa qb qc ...]
#define O_AUX  1583424  // thr[32] + R0[64]
#define O_WFR  1583552  // float2 per edge (wf, wr)
#define O_TFS  2107840  // fp16 [E][64] = tf*score
#define O_CNTS 10496448 // int[4096]
#define O_CNTT 10500544 // int[4096]
#define O_ELS  10504640 // int[4096][192]
#define O_ELT  11291072 // int[4096][192]
#define O_QB   12077504 // bf16 [4][4096][32] (scaled by log2e/sqrt(d))
#define O_KB   12339648
#define O_VT   12601792 // bf16 [4][32][4096]

typedef __attribute__((ext_vector_type(8))) short short8v;
typedef __attribute__((ext_vector_type(4))) float f32x4;

__device__ __forceinline__ ushort f2bf(float x) {
    uint u = __builtin_bit_cast(uint, x);
    uint r = (u + 0x7FFFu + ((u >> 16) & 1u)) >> 16;
    return (ushort)r;
}
__device__ __forceinline__ float fexp2(float x) { return __builtin_amdgcn_exp2f(x); }

// ---------------- K0: region tables for piecewise-linear temporal MLP ----------------
// grid = 33 blocks (one per region), 64 threads.
__global__ __launch_bounds__(64) void k_setup(
    const float* __restrict__ te_w1, const float* __restrict__ te_b1,
    const float* __restrict__ te_w2, const float* __restrict__ te_b2,
    const float* __restrict__ ln_g, const float* __restrict__ ln_b,
    const float* __restrict__ sc_w1, float* __restrict__ tab, float* __restrict__ aux)
{
    __shared__ float t_s[32];
    __shared__ int pos_s[32];
    __shared__ float AG_s[64], BG_s[64];
    int r = blockIdx.x;
    int c = threadIdx.x;
    if (c < 32) {
        float w = te_w1[c], b = te_b1[c];
        t_s[c] = (w != 0.f) ? (-b / w) : 1e30f;
    }
    __syncthreads();
    if (c < 32) {
        float t = t_s[c];
        int p = 0;
        for (int i = 0; i < 32; i++) {
            float ti = t_s[i];
            p += (ti < t) || (ti == t && i < c);
        }
        pos_s[c] = p;
    }
    __syncthreads();
    float A = 0.f, B = te_b2[c];
    for (int j = 0; j < 32; j++) {
        float w = te_w1[j], b = te_b1[j];
        bool act = (w > 0.f) ? (pos_s[j] < r) : ((w < 0.f) ? (pos_s[j] >= r) : (b > 0.f));
        if (act) { float w2 = te_w2[c*32 + j]; A += w * w2; B += b * w2; }
    }
    float mA = A, mB = B;
    #pragma unroll
    for (int m = 32; m >= 1; m >>= 1) { mA += __shfl_xor(mA, m, 64); mB += __shfl_xor(mB, m, 64); }
    mA *= (1.f/64.f); mB *= (1.f/64.f);
    float a = A - mA, bq = B - mB;
    float qa = a*a, qb = a*bq, qc = bq*bq;
    #pragma unroll
    for (int m = 32; m >= 1; m >>= 1) {
        qa += __shfl_xor(qa, m, 64); qb += __shfl_xor(qb, m, 64); qc += __shfl_xor(qc, m, 64);
    }
    qa *= (1.f/64.f); qb *= (2.f/64.f); qc *= (1.f/64.f);
    float g = ln_g[c];
    float AG = a*g, BG = bq*g;
    AG_s[c] = AG; BG_s[c] = BG;
    float* row = tab + r*320;
    row[c] = AG; row[64+c] = BG;
    if (c == 0) { row[256] = qa; row[257] = qb; row[258] = qc; }
    __syncthreads();
    const float* wc = sc_w1 + c*320 + 256;  // Wc[c][0..63]
    float P = 0.f, Q = 0.f;
    for (int j = 0; j < 64; j++) { float w = wc[j]; P += AG_s[j]*w; Q += BG_s[j]*w; }
    row[128+c] = P; row[192+c] = Q;
    if (r == 0) {
        if (c < 32) aux[pos_s[c]] = t_s[c];
        float R0 = 0.f;
        for (int j = 0; j < 64; j++) R0 += ln_b[j] * wc[j];
        aux[32 + c] = R0;
    }
}

// ---------------- K1: xp = x@inp_w.T+b ; q,k,v projections -> bf16 qb,kb,vt ----------------
__global__ __launch_bounds__(128) void k_proj_qkv(
    const float* __restrict__ x, const float* __restrict__ inp_w, const float* __restrict__ inp_b,
    const float* __restrict__ wq, const float* __restrict__ bq,
    const float* __restrict__ wk, const float* __restrict__ bk,
    const float* __restrict__ wv, const float* __restrict__ bv,
    ushort* __restrict__ qb, ushort* __restrict__ kbuf, ushort* __restrict__ vt)
{
    __shared__ float xs[128];
    __shared__ float xps[128];
    int n = blockIdx.x;
    int c = threadIdx.x;
    xs[c] = x[n*128 + c];
    __syncthreads();
    float acc = inp_b[c];
    const float* wrow = inp_w + c*128;
    #pragma unroll 8
    for (int i = 0; i < 128; i++) acc += xs[i] * wrow[i];
    xps[c] = acc;
    __syncthreads();
    float aq = bq[c], ak = bk[c], av = bv[c];
    const float* qrow = wq + c*128;
    const float* krow = wk + c*128;
    const float* vrow = wv + c*128;
    #pragma unroll 4
    for (int i = 0; i < 128; i++) {
        float xv = xps[i];
        aq += xv * qrow[i];
        ak += xv * krow[i];
        av += xv * vrow[i];
    }
    const float QSCALE = 0.17677669529663687f * 1.4426950408889634f;
    int h = c >> 5, d = c & 31;
    int qi = h*131072 + n*32 + d;
    qb[qi]   = f2bf(aq * QSCALE);
    kbuf[qi] = f2bf(ak);
    vt[c*4096 + n] = f2bf(av);
}

// ---------------- K2: MFMA flash attention (unchanged) ----------------
__global__ __launch_bounds__(256) void k_attn(
    const ushort* __restrict__ qb, const ushort* __restrict__ kb,
    const ushort* __restrict__ vt, float* __restrict__ ctxT)
{
    __shared__ float mbuf[4][16];
    __shared__ float lbuf[4][16];
    __shared__ float obuf[4][512];
    int tid = threadIdx.x;
    int lane = tid & 63;
    int wv = tid >> 6;
    int h = blockIdx.x & 3;
    int qt = blockIdx.x >> 2;
    int q15 = lane & 15;
    int g = lane >> 4;
    const ushort* qhb = qb + h*131072;
    const ushort* khb = kb + h*131072;
    const ushort* vhb = vt + h*131072;
    short8v qf = *(const short8v*)(qhb + (qt*16 + q15)*32 + g*8);
    int key0off = ((q15 >> 2) << 3) + (q15 & 3);
    f32x4 o0 = {0.f,0.f,0.f,0.f}, o1 = {0.f,0.f,0.f,0.f};
    const f32x4 z = {0.f,0.f,0.f,0.f};
    float m_run = -1e30f, l_run = 0.f;
    int kstart = wv * 1024;
    for (int k32 = kstart; k32 < kstart + 1024; k32 += 32) {
        short8v kf0 = *(const short8v*)(khb + (k32 + key0off)*32 + g*8);
        short8v kf1 = *(const short8v*)(khb + (k32 + key0off + 4)*32 + g*8);
        short8v vf0 = *(const short8v*)(vhb + q15*4096 + k32 + g*8);
        short8v vf1 = *(const short8v*)(vhb + (16 + q15)*4096 + k32 + g*8);
        f32x4 s0 = __builtin_amdgcn_mfma_f32_16x16x32_bf16(kf0, qf, z, 0, 0, 0);
        f32x4 s1 = __builtin_amdgcn_mfma_f32_16x16x32_bf16(kf1, qf, z, 0, 0, 0);
        float tmax = fmaxf(fmaxf(fmaxf(s0[0], s0[1]), fmaxf(s0[2], s0[3])),
                           fmaxf(fmaxf(s1[0], s1[1]), fmaxf(s1[2], s1[3])));
        tmax = fmaxf(tmax, __shfl_xor(tmax, 16, 64));
        tmax = fmaxf(tmax, __shfl_xor(tmax, 32, 64));
        float mnew = fmaxf(m_run, tmax);
        float sc = fexp2(m_run - mnew);
        float p0 = fexp2(s0[0] - mnew), p1 = fexp2(s0[1] - mnew);
        float p2 = fexp2(s0[2] - mnew), p3 = fexp2(s0[3] - mnew);
        float p4 = fexp2(s1[0] - mnew), p5 = fexp2(s1[1] - mnew);
        float p6 = fexp2(s1[2] - mnew), p7 = fexp2(s1[3] - mnew);
        float psum = ((p0 + p1) + (p2 + p3)) + ((p4 + p5) + (p6 + p7));
        psum += __shfl_xor(psum, 16, 64);
        psum += __shfl_xor(psum, 32, 64);
        l_run = l_run * sc + psum;
        m_run = mnew;
        #pragma unroll
        for (int r = 0; r < 4; r++) { o0[r] *= sc; o1[r] *= sc; }
        short8v pf;
        pf[0] = (short)f2bf(p0); pf[1] = (short)f2bf(p1);
        pf[2] = (short)f2bf(p2); pf[3] = (short)f2bf(p3);
        pf[4] = (short)f2bf(p4); pf[5] = (short)f2bf(p5);
        pf[6] = (short)f2bf(p6); pf[7] = (short)f2bf(p7);
        o0 = __builtin_amdgcn_mfma_f32_16x16x32_bf16(vf0, pf, o0, 0, 0, 0);
        o1 = __builtin_amdgcn_mfma_f32_16x16x32_bf16(vf1, pf, o1, 0, 0, 0);
    }
    if (lane < 16) { mbuf[wv][lane] = m_run; lbuf[wv][lane] = l_run; }
    #pragma unroll
    for (int r = 0; r < 4; r++) {
        obuf[wv][r*64 + lane]       = o0[r];
        obuf[wv][(4 + r)*64 + lane] = o1[r];
    }
    __syncthreads();
    for (int e = tid; e < 512; e += 256) {
        int lp = e & 63, r8 = e >> 6;
        int q = lp & 15;
        float m0 = mbuf[0][q], m1 = mbuf[1][q], m2 = mbuf[2][q], m3 = mbuf[3][q];
        float M = fmaxf(fmaxf(m0, m1), fmaxf(m2, m3));
        float sc0 = fexp2(m0 - M), sc1 = fexp2(m1 - M);
        float sc2 = fexp2(m2 - M), sc3 = fexp2(m3 - M);
        float L = lbuf[0][q]*sc0 + lbuf[1][q]*sc1 + lbuf[2][q]*sc2 + lbuf[3][q]*sc3;
        float a = obuf[0][e]*sc0 + obuf[1][e]*sc1 + obuf[2][e]*sc2 + obuf[3][e]*sc3;
        int d = ((lp >> 4) << 2) + (r8 & 3) + ((r8 >> 2) << 4);
        ctxT[(h*32 + d)*4096 + qt*16 + q] = a / L;
    }
}

// ---------------- K3: attn_out + outp (fused, per node) ----------------
__global__ __launch_bounds__(128) void k_out_base(
    const float* __restrict__ ctxT, const float* __restrict__ aw, const float* __restrict__ ab,
    const float* __restrict__ ow, const float* __restrict__ ob, float* __restrict__ base)
{
    __shared__ float cs[128];
    __shared__ float as[128];
    int n = blockIdx.x, c = threadIdx.x;
    cs[c] = ctxT[c*4096 + n];
    __syncthreads();
    float acc = ab[c];
    const float* wr = aw + c*128;
    #pragma unroll 8
    for (int i = 0; i < 128; i++) acc += cs[i]*wr[i];
    as[c] = acc;
    __syncthreads();
    float acc2 = ob[c];
    const float* wr2 = ow + c*128;
    #pragma unroll 8
    for (int i = 0; i < 128; i++) acc2 += as[i]*wr2[i];
    base[n*128+c] = acc2;
}

// ---------------- K6a: per-node sc-MLP x partials ----------------
__global__ __launch_bounds__(128) void k_node_sc(
    const float* __restrict__ x, const float* __restrict__ sc_w1,
    float* __restrict__ xsa, float* __restrict__ xtb)
{
    __shared__ float xs[128];
    int n = blockIdx.x, c = threadIdx.x;
    xs[c] = x[n*128+c];
    __syncthreads();
    int r = c & 63;
    const float* wr = sc_w1 + r*320 + ((c >= 64) ? 128 : 0);
    float acc = 0.f;
    #pragma unroll 8
    for (int i = 0; i < 128; i++) acc += xs[i]*wr[i];
    if (c < 64) xsa[n*64+r] = acc; else xtb[n*64+r] = acc;
}

// ---------------- K4: bin edges into per-node lists (both directions) ----------------
__global__ __launch_bounds__(256) void k_fill(
    const int* __restrict__ eidx, int* __restrict__ cnt_s, int* __restrict__ cnt_t,
    int* __restrict__ els, int* __restrict__ elt)
{
    int e = blockIdx.x*256 + threadIdx.x;
    int s = eidx[e], t = eidx[N_EDGES + e];
    int p = atomicAdd(&cnt_s[s], 1);
    if (p < CAP) els[s*CAP + p] = e;
    int q = atomicAdd(&cnt_t[t], 1);
    if (q < CAP) elt[t*CAP + q] = e;
}

// ---------------- K6: per-edge via PWL tables: tf*score (fp16) + edge weights ----------------
// wave per edge, 2 edges per wave-iter for ILP; grid 2048 x 4 waves.
__global__ __launch_bounds__(256) void k_edge(
    const int* __restrict__ eidx, const float* __restrict__ etime,
    const float* __restrict__ eattr,
    const float* __restrict__ tab, const float* __restrict__ aux,
    const float* __restrict__ sc_b1, const float* __restrict__ sc_w2,
    const float* __restrict__ sc_b2, const float* __restrict__ ln_b,
    const float* __restrict__ decay_p,
    const float* __restrict__ xsa, const float* __restrict__ xtb,
    ushort* __restrict__ tfs, float2* __restrict__ wfr)
{
    int tid = threadIdx.x;
    int lane = tid & 63;
    int wv = tid >> 6;
    float thr = 0.f;
    if (lane < 32) thr = aux[lane];
    float R0  = aux[32 + lane];
    float sb1 = sc_b1[lane], sw2 = sc_w2[lane], lnb = ln_b[lane];
    float decay = decay_p[0];
    float sb2 = sc_b2[0];
    for (int base_e = blockIdx.x*8; base_e < N_EDGES; base_e += 2048*8) {
        #pragma unroll
        for (int ii = 0; ii < 2; ii++) {
            int e = base_e + wv + ii*4;
            int src = eidx[e];
            int tgt = eidx[N_EDGES + e];
            float t = etime[e];
            float wt = t * __expf(-fabsf(t)*decay);
            bool pr = (lane < 32) && (wt > thr);
            int r = __popcll(__ballot(pr));
            const float* row = tab + r*320;
            float AG = row[lane], BG = row[64+lane];
            float P  = row[128+lane], Q = row[192+lane];
            float qa = row[256], qb = row[257], qc = row[258];
            float isd = rsqrtf(fmaf(fmaf(qa, wt, qb), wt, qc) + EPS);
            float tf = fmaf(isd, fmaf(AG, wt, BG), lnb);
            float u = sb1 + xsa[src*64 + lane] + xtb[tgt*64 + lane] + R0;
            float rh = fmaf(isd, fmaf(P, wt, Q), u);
            rh = fmaxf(rh, 0.f);
            float ps = rh * sw2;
            #pragma unroll
            for (int m = 32; m >= 1; m >>= 1) ps += __shfl_xor(ps, m, 64);
            float score = 1.f / (1.f + __expf(-(ps + sb2)));
            __half hv = __float2half(tf * score);
            tfs[e*64 + lane] = __builtin_bit_cast(ushort, hv);
            if (lane == 0) {
                float hier = eattr[e*17 + 16];
                float tfj  = eattr[e*17 + 5];
                float wf = 0.f, wr2 = 0.f;
                if (hier > 0.f) {
                    wf  = hier * (1.f/(1.f + __expf(-tfj))) * 0.3f;
                    wr2 = hier * 0.1f;
                }
                wfr[e] = make_float2(wf, wr2);
            }
        }
    }
}

// ---------------- K7: gather upd+nctx, agg GEMM + LN + relu ----------------
__global__ __launch_bounds__(256) void k_final(
    const float* __restrict__ base, const ushort* __restrict__ tfs,
    const float2* __restrict__ wfr, const int* __restrict__ eidx,
    const int* __restrict__ cnt_s, const int* __restrict__ cnt_t,
    const int* __restrict__ els, const int* __restrict__ elt,
    const float* __restrict__ agg_w, const float* __restrict__ agg_b,
    const float* __restrict__ g, const float* __restrict__ b, float* __restrict__ out)
{
    __shared__ float comb[192];
    __shared__ float nadd[2][64];
    __shared__ float red[8];
    int n = blockIdx.x, tid = threadIdx.x;
    int ns  = min(cnt_s[n], CAP);
    int ntg = min(cnt_t[n], CAP);
    if (tid < 128) {
        int c = tid;
        float acc = base[n*128 + c];
        const int* ls = els + n*CAP;
        int i = 0;
        for (; i + 1 < ns; i += 2) {
            int e0 = ls[i], e1 = ls[i+1];
            int t0 = eidx[N_EDGES + e0], t1 = eidx[N_EDGES + e1];
            float w0 = wfr[e0].x, w1 = wfr[e1].x;
            acc += base[t0*128 + c]*w0 + base[t1*128 + c]*w1;
        }
        if (i < ns) {
            int e0 = ls[i];
            acc += base[eidx[N_EDGES + e0]*128 + c] * wfr[e0].x;
        }
        const int* lt = elt + n*CAP;
        i = 0;
        for (; i + 1 < ntg; i += 2) {
            int e0 = lt[i], e1 = lt[i+1];
            int s0 = eidx[e0], s1 = eidx[e1];
            float w0 = wfr[e0].y, w1 = wfr[e1].y;
            acc += base[s0*128 + c]*w0 + base[s1*128 + c]*w1;
        }
        if (i < ntg) {
            int e0 = lt[i];
            acc += base[eidx[e0]*128 + c] * wfr[e0].y;
        }
        comb[c] = acc;
    } else {
        int c = (tid - 128) & 63, hh = (tid - 128) >> 6;
        const int* ls = els + n*CAP;
        float acc = 0.f;
        for (int i = hh; i < ns; i += 2) {
            int e = ls[i];
            ushort u = tfs[e*64 + c];
            acc += __half2float(__builtin_bit_cast(__half, u));
        }
        nadd[hh][c] = acc;
    }
    __syncthreads();
    if (tid >= 128 && tid < 192) comb[tid] = nadd[0][tid-128] + nadd[1][tid-128];
    __syncthreads();
    int c = tid;
    float acc = agg_b[c];
    const float* wr = agg_w + c*192;
    #pragma unroll 4
    for (int i = 0; i < 192; i++) acc += comb[i]*wr[i];
    int lane = c & 63, w = c >> 6;
    float s = acc;
    #pragma unroll
    for (int m = 32; m >= 1; m >>= 1) s += __shfl_xor(s, m, 64);
    if (lane == 0) red[w] = s;
    __syncthreads();
    float mu = (red[0]+red[1]+red[2]+red[3]) * (1.f/256.f);
    float d = acc - mu;
    float s2 = d*d;
    #pragma unroll
    for (int m = 32; m >= 1; m >>= 1) s2 += __shfl_xor(s2, m, 64);
    if (lane == 0) red[4+w] = s2;
    __syncthreads();
    float var = (red[4]+red[5]+red[6]+red[7]) * (1.f/256.f);
    float y = d * rsqrtf(var + EPS) * g[c] + b[c];
    out[n*256+c] = fmaxf(y, 0.f);
}

extern "C" void kernel_launch(void* const* d_in, const int* in_sizes, int n_in,
                              void* d_out, int out_size, void* d_ws, size_t ws_size,
                              hipStream_t stream)
{
    const float* x        = (const float*)d_in[0];
    const int*   eidx     = (const int*)d_in[1];
    const float* etime    = (const float*)d_in[2];
    const float* eattr    = (const float*)d_in[3];
    const float* te_w1    = (const float*)d_in[4];
    const float* te_b1    = (const float*)d_in[5];
    const float* te_w2    = (const float*)d_in[6];
    const float* te_b2    = (const float*)d_in[7];
    const float* te_ln_g  = (const float*)d_in[8];
    const float* te_ln_b  = (const float*)d_in[9];
    const float* inp_w    = (const float*)d_in[10];
    const float* inp_b    = (const float*)d_in[11];
    const float* wq       = (const float*)d_in[12];
    const float* bq       = (const float*)d_in[13];
    const float* wk       = (const float*)d_in[14];
    const float* bk       = (const float*)d_in[15];
    const float* wv       = (const float*)d_in[16];
    const float* bv       = (const float*)d_in[17];
    const float* aow      = (const float*)d_in[18];
    const float* aob      = (const float*)d_in[19];
    const float* ow       = (const float*)d_in[20];
    const float* ob       = (const float*)d_in[21];
    const float* sc_w1    = (const float*)d_in[22];
    const float* sc_b1    = (const float*)d_in[23];
    const float* sc_w2    = (const float*)d_in[24];
    const float* sc_b2    = (const float*)d_in[25];
    const float* agg_w    = (const float*)d_in[26];
    const float* agg_b    = (const float*)d_in[27];
    const float* agg_g    = (const float*)d_in[28];
    const float* agg_bb   = (const float*)d_in[29];
    const float* decay    = (const float*)d_in[30];
    float* ws = (float*)d_ws;
    float* out = (float*)d_out;
    ushort* qb   = (ushort*)(ws + O_QB);
    ushort* kbuf = (ushort*)(ws + O_KB);
    ushort* vt   = (ushort*)(ws + O_VT);
    ushort* tfs  = (ushort*)(ws + O_TFS);
    float2* wfr  = (float2*)(ws + O_WFR);
    int* cnt_s   = (int*)(ws + O_CNTS);
    int* cnt_t   = (int*)(ws + O_CNTT);
    int* els     = (int*)(ws + O_ELS);
    int* elt     = (int*)(ws + O_ELT);

    // zero edge-bin counters (cnt_s and cnt_t are contiguous)
    hipMemsetAsync(ws + O_CNTS, 0, 8192*sizeof(int), stream);

    k_setup<<<33, 64, 0, stream>>>(te_w1, te_b1, te_w2, te_b2, te_ln_g, te_ln_b,
                                   sc_w1, ws+O_TAB, ws+O_AUX);
    k_proj_qkv<<<N_NODES, 128, 0, stream>>>(x, inp_w, inp_b, wq, bq, wk, bk, wv, bv,
                                            qb, kbuf, vt);
    k_node_sc<<<N_NODES, 128, 0, stream>>>(x, sc_w1, ws+O_XSA, ws+O_XTB);
    k_fill<<<N_EDGES/256, 256, 0, stream>>>(eidx, cnt_s, cnt_t, els, elt);
    k_edge<<<2048, 256, 0, stream>>>(eidx, etime, eattr, ws+O_TAB, ws+O_AUX,
                                     sc_b1, sc_w2, sc_b2, te_ln_b, decay,
                                     ws+O_XSA, ws+O_XTB, tfs, wfr);
    k_attn<<<1024, 256, 0, stream>>>(qb, kbuf, vt, ws+O_CTXT);
    k_out_base<<<N_NODES, 128, 0, stream>>>(ws+O_CTXT, aow, aob, ow, ob, ws+O_BASE);
    k_final<<<N_NODES, 256, 0, stream>>>(ws+O_BASE, tfs, wfr, eidx, cnt_s, cnt_t,
                                         els, elt, agg_w, agg_b, agg_g, agg_bb, out);
}

// Round 4
// 668.826 us; speedup vs baseline: 1.7957x; 1.0174x over previous
//
#include <hip/hip_runtime.h>

#define N_NODES 4096
#define N_EDGES 262144
#define EPS 1e-5f
#define CAP 192

// workspace offsets (float units)
#define O_CTXT 0        // ctx^T f32 [128][4096]
#define O_BASE 524288   // base [4096][128]
#define O_XSA  1048576
#define O_XTB  1310720
#define O_TAB  1572864  // 33 regions x 320: [AG 64][BG 64][P 64][Q 64][qa qb qc ...]
#define O_AUX  1583424  // thr[32] + R0[64]
#define O_RECS 1583552  // float4 [4096][CAP]  {pack(tgt,r), wf, s1, s2}
#define O_RECT 4729280  // float2 [4096][CAP]  {src, wr}
#define O_SLS  6302144  // int[E] slot in src list
#define O_SLT  6564288  // int[E] slot in tgt list
#define O_CNTS 6826432  // int[4096]
#define O_CNTT 6830528  // int[4096]
#define O_NSC  6834624  // float[4096] sum of scores per src
#define O_QB   6838720  // bf16 [4][4096][32] (scaled by log2e/sqrt(d))
#define O_KB   7100864
#define O_VT   7363008  // bf16 [4][32][4096]

typedef __attribute__((ext_vector_type(8))) short short8v;
typedef __attribute__((ext_vector_type(4))) float f32x4;

__device__ __forceinline__ ushort f2bf(float x) {
    uint u = __builtin_bit_cast(uint, x);
    uint r = (u + 0x7FFFu + ((u >> 16) & 1u)) >> 16;
    return (ushort)r;
}
__device__ __forceinline__ float fexp2(float x) { return __builtin_amdgcn_exp2f(x); }

// ---------------- K0: region tables for piecewise-linear temporal MLP ----------------
__global__ __launch_bounds__(64) void k_setup(
    const float* __restrict__ te_w1, const float* __restrict__ te_b1,
    const float* __restrict__ te_w2, const float* __restrict__ te_b2,
    const float* __restrict__ ln_g, const float* __restrict__ ln_b,
    const float* __restrict__ sc_w1, float* __restrict__ tab, float* __restrict__ aux)
{
    __shared__ float t_s[32];
    __shared__ int pos_s[32];
    __shared__ float AG_s[64], BG_s[64];
    int r = blockIdx.x;
    int c = threadIdx.x;
    if (c < 32) {
        float w = te_w1[c], b = te_b1[c];
        t_s[c] = (w != 0.f) ? (-b / w) : 1e30f;
    }
    __syncthreads();
    if (c < 32) {
        float t = t_s[c];
        int p = 0;
        for (int i = 0; i < 32; i++) {
            float ti = t_s[i];
            p += (ti < t) || (ti == t && i < c);
        }
        pos_s[c] = p;
    }
    __syncthreads();
    float A = 0.f, B = te_b2[c];
    for (int j = 0; j < 32; j++) {
        float w = te_w1[j], b = te_b1[j];
        bool act = (w > 0.f) ? (pos_s[j] < r) : ((w < 0.f) ? (pos_s[j] >= r) : (b > 0.f));
        if (act) { float w2 = te_w2[c*32 + j]; A += w * w2; B += b * w2; }
    }
    float mA = A, mB = B;
    #pragma unroll
    for (int m = 32; m >= 1; m >>= 1) { mA += __shfl_xor(mA, m, 64); mB += __shfl_xor(mB, m, 64); }
    mA *= (1.f/64.f); mB *= (1.f/64.f);
    float a = A - mA, bq = B - mB;
    float qa = a*a, qb = a*bq, qc = bq*bq;
    #pragma unroll
    for (int m = 32; m >= 1; m >>= 1) {
        qa += __shfl_xor(qa, m, 64); qb += __shfl_xor(qb, m, 64); qc += __shfl_xor(qc, m, 64);
    }
    qa *= (1.f/64.f); qb *= (2.f/64.f); qc *= (1.f/64.f);
    float g = ln_g[c];
    float AG = a*g, BG = bq*g;
    AG_s[c] = AG; BG_s[c] = BG;
    float* row = tab + r*320;
    row[c] = AG; row[64+c] = BG;
    if (c == 0) { row[256] = qa; row[257] = qb; row[258] = qc; }
    __syncthreads();
    const float* wc = sc_w1 + c*320 + 256;  // Wc[c][0..63]
    float P = 0.f, Q = 0.f;
    for (int j = 0; j < 64; j++) { float w = wc[j]; P += AG_s[j]*w; Q += BG_s[j]*w; }
    row[128+c] = P; row[192+c] = Q;
    if (r == 0) {
        if (c < 32) aux[pos_s[c]] = t_s[c];
        float R0 = 0.f;
        for (int j = 0; j < 64; j++) R0 += ln_b[j] * wc[j];
        aux[32 + c] = R0;
    }
}

// ---------------- K1: xp = x@inp_w.T+b ; q,k,v projections -> bf16 qb,kb,vt ----------------
__global__ __launch_bounds__(128) void k_proj_qkv(
    const float* __restrict__ x, const float* __restrict__ inp_w, const float* __restrict__ inp_b,
    const float* __restrict__ wq, const float* __restrict__ bq,
    const float* __restrict__ wk, const float* __restrict__ bk,
    const float* __restrict__ wv, const float* __restrict__ bv,
    ushort* __restrict__ qb, ushort* __restrict__ kbuf, ushort* __restrict__ vt)
{
    __shared__ float xs[128];
    __shared__ float xps[128];
    int n = blockIdx.x;
    int c = threadIdx.x;
    xs[c] = x[n*128 + c];
    __syncthreads();
    float acc = inp_b[c];
    const float* wrow = inp_w + c*128;
    #pragma unroll 8
    for (int i = 0; i < 128; i++) acc += xs[i] * wrow[i];
    xps[c] = acc;
    __syncthreads();
    float aq = bq[c], ak = bk[c], av = bv[c];
    const float* qrow = wq + c*128;
    const float* krow = wk + c*128;
    const float* vrow = wv + c*128;
    #pragma unroll 4
    for (int i = 0; i < 128; i++) {
        float xv = xps[i];
        aq += xv * qrow[i];
        ak += xv * krow[i];
        av += xv * vrow[i];
    }
    const float QSCALE = 0.17677669529663687f * 1.4426950408889634f;
    int h = c >> 5, d = c & 31;
    int qi = h*131072 + n*32 + d;
    qb[qi]   = f2bf(aq * QSCALE);
    kbuf[qi] = f2bf(ak);
    vt[c*4096 + n] = f2bf(av);
}

// ---------------- K2: MFMA flash attention (unchanged) ----------------
__global__ __launch_bounds__(256) void k_attn(
    const ushort* __restrict__ qb, const ushort* __restrict__ kb,
    const ushort* __restrict__ vt, float* __restrict__ ctxT)
{
    __shared__ float mbuf[4][16];
    __shared__ float lbuf[4][16];
    __shared__ float obuf[4][512];
    int tid = threadIdx.x;
    int lane = tid & 63;
    int wv = tid >> 6;
    int h = blockIdx.x & 3;
    int qt = blockIdx.x >> 2;
    int q15 = lane & 15;
    int g = lane >> 4;
    const ushort* qhb = qb + h*131072;
    const ushort* khb = kb + h*131072;
    const ushort* vhb = vt + h*131072;
    short8v qf = *(const short8v*)(qhb + (qt*16 + q15)*32 + g*8);
    int key0off = ((q15 >> 2) << 3) + (q15 & 3);
    f32x4 o0 = {0.f,0.f,0.f,0.f}, o1 = {0.f,0.f,0.f,0.f};
    const f32x4 z = {0.f,0.f,0.f,0.f};
    float m_run = -1e30f, l_run = 0.f;
    int kstart = wv * 1024;
    for (int k32 = kstart; k32 < kstart + 1024; k32 += 32) {
        short8v kf0 = *(const short8v*)(khb + (k32 + key0off)*32 + g*8);
        short8v kf1 = *(const short8v*)(khb + (k32 + key0off + 4)*32 + g*8);
        short8v vf0 = *(const short8v*)(vhb + q15*4096 + k32 + g*8);
        short8v vf1 = *(const short8v*)(vhb + (16 + q15)*4096 + k32 + g*8);
        f32x4 s0 = __builtin_amdgcn_mfma_f32_16x16x32_bf16(kf0, qf, z, 0, 0, 0);
        f32x4 s1 = __builtin_amdgcn_mfma_f32_16x16x32_bf16(kf1, qf, z, 0, 0, 0);
        float tmax = fmaxf(fmaxf(fmaxf(s0[0], s0[1]), fmaxf(s0[2], s0[3])),
                           fmaxf(fmaxf(s1[0], s1[1]), fmaxf(s1[2], s1[3])));
        tmax = fmaxf(tmax, __shfl_xor(tmax, 16, 64));
        tmax = fmaxf(tmax, __shfl_xor(tmax, 32, 64));
        float mnew = fmaxf(m_run, tmax);
        float sc = fexp2(m_run - mnew);
        float p0 = fexp2(s0[0] - mnew), p1 = fexp2(s0[1] - mnew);
        float p2 = fexp2(s0[2] - mnew), p3 = fexp2(s0[3] - mnew);
        float p4 = fexp2(s1[0] - mnew), p5 = fexp2(s1[1] - mnew);
        float p6 = fexp2(s1[2] - mnew), p7 = fexp2(s1[3] - mnew);
        float psum = ((p0 + p1) + (p2 + p3)) + ((p4 + p5) + (p6 + p7));
        psum += __shfl_xor(psum, 16, 64);
        psum += __shfl_xor(psum, 32, 64);
        l_run = l_run * sc + psum;
        m_run = mnew;
        #pragma unroll
        for (int r = 0; r < 4; r++) { o0[r] *= sc; o1[r] *= sc; }
        short8v pf;
        pf[0] = (short)f2bf(p0); pf[1] = (short)f2bf(p1);
        pf[2] = (short)f2bf(p2); pf[3] = (short)f2bf(p3);
        pf[4] = (short)f2bf(p4); pf[5] = (short)f2bf(p5);
        pf[6] = (short)f2bf(p6); pf[7] = (short)f2bf(p7);
        o0 = __builtin_amdgcn_mfma_f32_16x16x32_bf16(vf0, pf, o0, 0, 0, 0);
        o1 = __builtin_amdgcn_mfma_f32_16x16x32_bf16(vf1, pf, o1, 0, 0, 0);
    }
    if (lane < 16) { mbuf[wv][lane] = m_run; lbuf[wv][lane] = l_run; }
    #pragma unroll
    for (int r = 0; r < 4; r++) {
        obuf[wv][r*64 + lane]       = o0[r];
        obuf[wv][(4 + r)*64 + lane] = o1[r];
    }
    __syncthreads();
    for (int e = tid; e < 512; e += 256) {
        int lp = e & 63, r8 = e >> 6;
        int q = lp & 15;
        float m0 = mbuf[0][q], m1 = mbuf[1][q], m2 = mbuf[2][q], m3 = mbuf[3][q];
        float M = fmaxf(fmaxf(m0, m1), fmaxf(m2, m3));
        float sc0 = fexp2(m0 - M), sc1 = fexp2(m1 - M);
        float sc2 = fexp2(m2 - M), sc3 = fexp2(m3 - M);
        float L = lbuf[0][q]*sc0 + lbuf[1][q]*sc1 + lbuf[2][q]*sc2 + lbuf[3][q]*sc3;
        float a = obuf[0][e]*sc0 + obuf[1][e]*sc1 + obuf[2][e]*sc2 + obuf[3][e]*sc3;
        int d = ((lp >> 4) << 2) + (r8 & 3) + ((r8 >> 2) << 4);
        ctxT[(h*32 + d)*4096 + qt*16 + q] = a / L;
    }
}

// ---------------- K3: attn_out + outp (fused, per node) ----------------
__global__ __launch_bounds__(128) void k_out_base(
    const float* __restrict__ ctxT, const float* __restrict__ aw, const float* __restrict__ ab,
    const float* __restrict__ ow, const float* __restrict__ ob, float* __restrict__ base)
{
    __shared__ float cs[128];
    __shared__ float as[128];
    int n = blockIdx.x, c = threadIdx.x;
    cs[c] = ctxT[c*4096 + n];
    __syncthreads();
    float acc = ab[c];
    const float* wr = aw + c*128;
    #pragma unroll 8
    for (int i = 0; i < 128; i++) acc += cs[i]*wr[i];
    as[c] = acc;
    __syncthreads();
    float acc2 = ob[c];
    const float* wr2 = ow + c*128;
    #pragma unroll 8
    for (int i = 0; i < 128; i++) acc2 += as[i]*wr2[i];
    base[n*128+c] = acc2;
}

// ---------------- K6a: per-node sc-MLP x partials ----------------
__global__ __launch_bounds__(128) void k_node_sc(
    const float* __restrict__ x, const float* __restrict__ sc_w1,
    float* __restrict__ xsa, float* __restrict__ xtb)
{
    __shared__ float xs[128];
    int n = blockIdx.x, c = threadIdx.x;
    xs[c] = x[n*128+c];
    __syncthreads();
    int r = c & 63;
    const float* wr = sc_w1 + r*320 + ((c >= 64) ? 128 : 0);
    float acc = 0.f;
    #pragma unroll 8
    for (int i = 0; i < 128; i++) acc += xs[i]*wr[i];
    if (c < 64) xsa[n*64+r] = acc; else xtb[n*64+r] = acc;
}

// ---------------- K4: compute per-edge slots in src/tgt lists ----------------
__global__ __launch_bounds__(256) void k_fill(
    const int* __restrict__ eidx, int* __restrict__ cnt_s, int* __restrict__ cnt_t,
    int* __restrict__ slot_s, int* __restrict__ slot_t)
{
    int e = blockIdx.x*256 + threadIdx.x;
    int s = eidx[e], t = eidx[N_EDGES + e];
    slot_s[e] = atomicAdd(&cnt_s[s], 1);
    slot_t[e] = atomicAdd(&cnt_t[t], 1);
}

// ---------------- K6: per-edge PWL: packed records into per-node slots ----------------
__global__ __launch_bounds__(256) void k_edge(
    const int* __restrict__ eidx, const float* __restrict__ etime,
    const float* __restrict__ eattr,
    const float* __restrict__ tab, const float* __restrict__ aux,
    const float* __restrict__ sc_b1, const float* __restrict__ sc_w2,
    const float* __restrict__ sc_b2, const float* __restrict__ decay_p,
    const float* __restrict__ xsa, const float* __restrict__ xtb,
    const int* __restrict__ slot_s, const int* __restrict__ slot_t,
    float4* __restrict__ recS, float2* __restrict__ recT, float* __restrict__ nscore)
{
    int tid = threadIdx.x;
    int lane = tid & 63;
    int wv = tid >> 6;
    float thr = 0.f;
    if (lane < 32) thr = aux[lane];
    float R0  = aux[32 + lane];
    float sb1 = sc_b1[lane], sw2 = sc_w2[lane];
    float decay = decay_p[0];
    float sb2 = sc_b2[0];
    for (int base_e = blockIdx.x*8; base_e < N_EDGES; base_e += 2048*8) {
        #pragma unroll
        for (int ii = 0; ii < 2; ii++) {
            int e = base_e + wv + ii*4;
            int src = eidx[e];
            int tgt = eidx[N_EDGES + e];
            float t = etime[e];
            float wt = t * __expf(-fabsf(t)*decay);
            bool pr = (lane < 32) && (wt > thr);
            int r = __popcll(__ballot(pr));
            const float* row = tab + r*320;
            float P  = row[128+lane], Q = row[192+lane];
            float qa = row[256], qb = row[257], qc = row[258];
            float isd = rsqrtf(fmaf(fmaf(qa, wt, qb), wt, qc) + EPS);
            float u = sb1 + xsa[src*64 + lane] + xtb[tgt*64 + lane] + R0;
            float rh = fmaxf(fmaf(isd, fmaf(P, wt, Q), u), 0.f);
            float ps = rh * sw2;
            #pragma unroll
            for (int m = 32; m >= 1; m >>= 1) ps += __shfl_xor(ps, m, 64);
            float score = 1.f / (1.f + __expf(-(ps + sb2)));
            if (lane == 0) {
                atomicAdd(&nscore[src], score);
                float hier = eattr[e*17 + 16];
                float tfj  = eattr[e*17 + 5];
                float wf = 0.f, wr2 = 0.f;
                if (hier > 0.f) {
                    wf  = hier * (1.f/(1.f + __expf(-tfj))) * 0.3f;
                    wr2 = hier * 0.1f;
                }
                int ps_ = slot_s[e], pt_ = slot_t[e];
                if (ps_ < CAP) {
                    float4 rv;
                    rv.x = __builtin_bit_cast(float, (uint)(tgt | (r << 12)));
                    rv.y = wf;
                    rv.z = score * isd * wt;
                    rv.w = score * isd;
                    recS[src*CAP + ps_] = rv;
                }
                if (pt_ < CAP)
                    recT[tgt*CAP + pt_] = make_float2(__builtin_bit_cast(float, (uint)src), wr2);
            }
        }
    }
}

// ---------------- K7: stream records, gather base (L2), agg GEMM + LN + relu ----------------
__global__ __launch_bounds__(256) void k_final(
    const float* __restrict__ base, const float4* __restrict__ recS,
    const float2* __restrict__ recT, const int* __restrict__ cnt_s,
    const int* __restrict__ cnt_t, const float* __restrict__ nscore,
    const float* __restrict__ tab, const float* __restrict__ ln_b,
    const float* __restrict__ agg_w, const float* __restrict__ agg_b,
    const float* __restrict__ g, const float* __restrict__ b, float* __restrict__ out)
{
    __shared__ float agbg[33*128];   // [r][0..63]=AG, [r][64..127]=BG
    __shared__ float comb[192];
    __shared__ float nadd[2][64];
    __shared__ float red[8];
    int n = blockIdx.x, tid = threadIdx.x;
    for (int i = tid; i < 33*128; i += 256)
        agbg[i] = tab[(i >> 7)*320 + (i & 127)];
    __syncthreads();
    int ns = min(cnt_s[n], CAP);
    int nt = min(cnt_t[n], CAP);
    if (tid < 128) {
        int c = tid;
        float acc = base[n*128 + c];
        const float4* rs = recS + n*CAP;
        int i = 0;
        for (; i + 1 < ns; i += 2) {
            float4 r0 = rs[i], r1 = rs[i+1];
            int t0 = __builtin_bit_cast(uint, r0.x) & 4095;
            int t1 = __builtin_bit_cast(uint, r1.x) & 4095;
            acc += base[t0*128 + c]*r0.y + base[t1*128 + c]*r1.y;
        }
        if (i < ns) {
            float4 r0 = rs[i];
            acc += base[(__builtin_bit_cast(uint, r0.x) & 4095)*128 + c]*r0.y;
        }
        const float2* rt = recT + n*CAP;
        i = 0;
        for (; i + 1 < nt; i += 2) {
            float2 r0 = rt[i], r1 = rt[i+1];
            int s0 = __builtin_bit_cast(uint, r0.x);
            int s1 = __builtin_bit_cast(uint, r1.x);
            acc += base[s0*128 + c]*r0.y + base[s1*128 + c]*r1.y;
        }
        if (i < nt) {
            float2 r0 = rt[i];
            acc += base[(__builtin_bit_cast(uint, r0.x))*128 + c]*r0.y;
        }
        comb[c] = acc;
    } else {
        int c = (tid - 128) & 63, hh = (tid - 128) >> 6;
        const float4* rs = recS + n*CAP;
        float acc = 0.f;
        for (int i = hh; i < ns; i += 2) {
            float4 r0 = rs[i];
            int rg = (__builtin_bit_cast(uint, r0.x) >> 12) & 63;
            acc += r0.z*agbg[rg*128 + c] + r0.w*agbg[rg*128 + 64 + c];
        }
        nadd[hh][c] = acc;
    }
    __syncthreads();
    if (tid >= 128 && tid < 192) {
        int c = tid - 128;
        comb[tid] = nadd[0][c] + nadd[1][c] + nscore[n]*ln_b[c];
    }
    __syncthreads();
    int c = tid;
    float acc = agg_b[c];
    const float* wr = agg_w + c*192;
    #pragma unroll 4
    for (int i = 0; i < 192; i++) acc += comb[i]*wr[i];
    int lane = c & 63, w = c >> 6;
    float s = acc;
    #pragma unroll
    for (int m = 32; m >= 1; m >>= 1) s += __shfl_xor(s, m, 64);
    if (lane == 0) red[w] = s;
    __syncthreads();
    float mu = (red[0]+red[1]+red[2]+red[3]) * (1.f/256.f);
    float d = acc - mu;
    float s2 = d*d;
    #pragma unroll
    for (int m = 32; m >= 1; m >>= 1) s2 += __shfl_xor(s2, m, 64);
    if (lane == 0) red[4+w] = s2;
    __syncthreads();
    float var = (red[4]+red[5]+red[6]+red[7]) * (1.f/256.f);
    float y = d * rsqrtf(var + EPS) * g[c] + b[c];
    out[n*256+c] = fmaxf(y, 0.f);
}

extern "C" void kernel_launch(void* const* d_in, const int* in_sizes, int n_in,
                              void* d_out, int out_size, void* d_ws, size_t ws_size,
                              hipStream_t stream)
{
    const float* x        = (const float*)d_in[0];
    const int*   eidx     = (const int*)d_in[1];
    const float* etime    = (const float*)d_in[2];
    const float* eattr    = (const float*)d_in[3];
    const float* te_w1    = (const float*)d_in[4];
    const float* te_b1    = (const float*)d_in[5];
    const float* te_w2    = (const float*)d_in[6];
    const float* te_b2    = (const float*)d_in[7];
    const float* te_ln_g  = (const float*)d_in[8];
    const float* te_ln_b  = (const float*)d_in[9];
    const float* inp_w    = (const float*)d_in[10];
    const float* inp_b    = (const float*)d_in[11];
    const float* wq       = (const float*)d_in[12];
    const float* bq       = (const float*)d_in[13];
    const float* wk       = (const float*)d_in[14];
    const float* bk       = (const float*)d_in[15];
    const float* wv       = (const float*)d_in[16];
    const float* bv       = (const float*)d_in[17];
    const float* aow      = (const float*)d_in[18];
    const float* aob      = (const float*)d_in[19];
    const float* ow       = (const float*)d_in[20];
    const float* ob       = (const float*)d_in[21];
    const float* sc_w1    = (const float*)d_in[22];
    const float* sc_b1    = (const float*)d_in[23];
    const float* sc_w2    = (const float*)d_in[24];
    const float* sc_b2    = (const float*)d_in[25];
    const float* agg_w    = (const float*)d_in[26];
    const float* agg_b    = (const float*)d_in[27];
    const float* agg_g    = (const float*)d_in[28];
    const float* agg_bb   = (const float*)d_in[29];
    const float* decay    = (const float*)d_in[30];
    float* ws = (float*)d_ws;
    float* out = (float*)d_out;
    ushort* qb   = (ushort*)(ws + O_QB);
    ushort* kbuf = (ushort*)(ws + O_KB);
    ushort* vt   = (ushort*)(ws + O_VT);
    float4* recS = (float4*)(ws + O_RECS);
    float2* recT = (float2*)(ws + O_RECT);
    int* slot_s  = (int*)(ws + O_SLS);
    int* slot_t  = (int*)(ws + O_SLT);
    int* cnt_s   = (int*)(ws + O_CNTS);
    int* cnt_t   = (int*)(ws + O_CNTT);
    float* nscore = ws + O_NSC;

    // zero cnt_s, cnt_t, nscore (contiguous 12288 words)
    hipMemsetAsync(ws + O_CNTS, 0, 12288*sizeof(int), stream);

    k_setup<<<33, 64, 0, stream>>>(te_w1, te_b1, te_w2, te_b2, te_ln_g, te_ln_b,
                                   sc_w1, ws+O_TAB, ws+O_AUX);
    k_proj_qkv<<<N_NODES, 128, 0, stream>>>(x, inp_w, inp_b, wq, bq, wk, bk, wv, bv,
                                            qb, kbuf, vt);
    k_node_sc<<<N_NODES, 128, 0, stream>>>(x, sc_w1, ws+O_XSA, ws+O_XTB);
    k_fill<<<N_EDGES/256, 256, 0, stream>>>(eidx, cnt_s, cnt_t, slot_s, slot_t);
    k_edge<<<2048, 256, 0, stream>>>(eidx, etime, eattr, ws+O_TAB, ws+O_AUX,
                                     sc_b1, sc_w2, sc_b2, decay,
                                     ws+O_XSA, ws+O_XTB, slot_s, slot_t,
                                     recS, recT, nscore);
    k_attn<<<1024, 256, 0, stream>>>(qb, kbuf, vt, ws+O_CTXT);
    k_out_base<<<N_NODES, 128, 0, stream>>>(ws+O_CTXT, aow, aob, ow, ob, ws+O_BASE);
    k_final<<<N_NODES, 256, 0, stream>>>(ws+O_BASE, recS, recT, cnt_s, cnt_t, nscore,
                                         ws+O_TAB, te_ln_b,
                                         agg_w, agg_b, agg_g, agg_bb, out);
}

// Round 5
// 321.794 us; speedup vs baseline: 3.7322x; 2.0784x over previous
//
#include <hip/hip_runtime.h>

#define N_NODES 4096
#define N_EDGES 262144
#define EPS 1e-5f
#define CAP 192

// workspace offsets (float units)
#define O_CTXT 0        // ctx^T f32 [128][4096]
#define O_BASE 524288   // base [4096][128]
#define O_XSA  1048576
#define O_XTB  1310720
#define O_TAB  1572864  // 33 regions x 320
#define O_AUX  1583424  // thr[32] + R0[64]
#define O_RECS 1583552  // float4 [4096][CAP]
#define O_RECT 4729280  // float2 [4096][CAP]
#define O_SLS  6302144
#define O_SLT  6564288
#define O_CNTS 6826432
#define O_CNTT 6830528
#define O_NSC  6834624
#define O_QB   6838720  // bf16 [4][4096][32]
#define O_KB   7100864
#define O_VT   7363008  // bf16 [4][32][4096]
#define O_WT   7625152  // transposed weights
// within WT:
#define T_INP  0
#define T_WQ   16384
#define T_WK   32768
#define T_WV   49152
#define T_AW   65536
#define T_OW   81920
#define T_SC   98304
#define T_AGG  114688   // [192][256]

typedef __attribute__((ext_vector_type(8))) short short8v;
typedef __attribute__((ext_vector_type(4))) float f32x4;

__device__ __forceinline__ ushort f2bf(float x) {
    uint u = __builtin_bit_cast(uint, x);
    uint r = (u + 0x7FFFu + ((u >> 16) & 1u)) >> 16;
    return (ushort)r;
}
__device__ __forceinline__ float fexp2(float x) { return __builtin_amdgcn_exp2f(x); }

// ---------------- K-1: one-time weight transposes ----------------
__global__ __launch_bounds__(256) void k_tr(
    const float* __restrict__ inp_w, const float* __restrict__ wq,
    const float* __restrict__ wk, const float* __restrict__ wv,
    const float* __restrict__ aw, const float* __restrict__ ow,
    const float* __restrict__ sc_w1, const float* __restrict__ agg_w,
    float* __restrict__ wt)
{
    int idx = blockIdx.x*256 + threadIdx.x;
    if (idx < 114688) {
        int m = idx >> 14;
        int r = idx & 16383;
        int i = r >> 7, c = r & 127;
        float v;
        switch (m) {
            case 0: v = inp_w[c*128+i]; break;
            case 1: v = wq[c*128+i]; break;
            case 2: v = wk[c*128+i]; break;
            case 3: v = wv[c*128+i]; break;
            case 4: v = aw[c*128+i]; break;
            case 5: v = ow[c*128+i]; break;
            default: v = (c < 64) ? sc_w1[c*320+i] : sc_w1[(c-64)*320+128+i]; break;
        }
        wt[idx] = v;
    } else {
        int a = idx - 114688;
        int i = a >> 8, c = a & 255;
        wt[idx] = agg_w[c*192 + i];
    }
}

// ---------------- K0: region tables for piecewise-linear temporal MLP ----------------
__global__ __launch_bounds__(64) void k_setup(
    const float* __restrict__ te_w1, const float* __restrict__ te_b1,
    const float* __restrict__ te_w2, const float* __restrict__ te_b2,
    const float* __restrict__ ln_g, const float* __restrict__ ln_b,
    const float* __restrict__ sc_w1, float* __restrict__ tab, float* __restrict__ aux)
{
    __shared__ float t_s[32];
    __shared__ int pos_s[32];
    __shared__ float AG_s[64], BG_s[64];
    int r = blockIdx.x;
    int c = threadIdx.x;
    if (c < 32) {
        float w = te_w1[c], b = te_b1[c];
        t_s[c] = (w != 0.f) ? (-b / w) : 1e30f;
    }
    __syncthreads();
    if (c < 32) {
        float t = t_s[c];
        int p = 0;
        for (int i = 0; i < 32; i++) {
            float ti = t_s[i];
            p += (ti < t) || (ti == t && i < c);
        }
        pos_s[c] = p;
    }
    __syncthreads();
    float A = 0.f, B = te_b2[c];
    for (int j = 0; j < 32; j++) {
        float w = te_w1[j], b = te_b1[j];
        bool act = (w > 0.f) ? (pos_s[j] < r) : ((w < 0.f) ? (pos_s[j] >= r) : (b > 0.f));
        if (act) { float w2 = te_w2[c*32 + j]; A += w * w2; B += b * w2; }
    }
    float mA = A, mB = B;
    #pragma unroll
    for (int m = 32; m >= 1; m >>= 1) { mA += __shfl_xor(mA, m, 64); mB += __shfl_xor(mB, m, 64); }
    mA *= (1.f/64.f); mB *= (1.f/64.f);
    float a = A - mA, bq = B - mB;
    float qa = a*a, qb = a*bq, qc = bq*bq;
    #pragma unroll
    for (int m = 32; m >= 1; m >>= 1) {
        qa += __shfl_xor(qa, m, 64); qb += __shfl_xor(qb, m, 64); qc += __shfl_xor(qc, m, 64);
    }
    qa *= (1.f/64.f); qb *= (2.f/64.f); qc *= (1.f/64.f);
    float g = ln_g[c];
    float AG = a*g, BG = bq*g;
    AG_s[c] = AG; BG_s[c] = BG;
    float* row = tab + r*320;
    row[c] = AG; row[64+c] = BG;
    if (c == 0) { row[256] = qa; row[257] = qb; row[258] = qc; }
    __syncthreads();
    const float* wc = sc_w1 + c*320 + 256;
    float P = 0.f, Q = 0.f;
    for (int j = 0; j < 64; j++) { float w = wc[j]; P += AG_s[j]*w; Q += BG_s[j]*w; }
    row[128+c] = P; row[192+c] = Q;
    if (r == 0) {
        if (c < 32) aux[pos_s[c]] = t_s[c];
        float R0 = 0.f;
        for (int j = 0; j < 64; j++) R0 += ln_b[j] * wc[j];
        aux[32 + c] = R0;
    }
}

// ---------------- K1: projections with transposed (coalesced) weights ----------------
__global__ __launch_bounds__(128) void k_proj_qkv(
    const float* __restrict__ x, const float* __restrict__ wt,
    const float* __restrict__ inp_b,
    const float* __restrict__ bq, const float* __restrict__ bk, const float* __restrict__ bv,
    ushort* __restrict__ qb, ushort* __restrict__ kbuf, ushort* __restrict__ vt)
{
    __shared__ float xs[128];
    __shared__ float xps[128];
    int n = blockIdx.x;
    int c = threadIdx.x;
    xs[c] = x[n*128 + c];
    __syncthreads();
    float acc = inp_b[c];
    const float* inpT = wt + T_INP;
    #pragma unroll 8
    for (int i = 0; i < 128; i++) acc += xs[i] * inpT[i*128 + c];
    xps[c] = acc;
    __syncthreads();
    float aq = bq[c], ak = bk[c], av = bv[c];
    const float* wqT = wt + T_WQ;
    const float* wkT = wt + T_WK;
    const float* wvT = wt + T_WV;
    #pragma unroll 4
    for (int i = 0; i < 128; i++) {
        float xv = xps[i];
        aq += xv * wqT[i*128 + c];
        ak += xv * wkT[i*128 + c];
        av += xv * wvT[i*128 + c];
    }
    const float QSCALE = 0.17677669529663687f * 1.4426950408889634f;
    int h = c >> 5, d = c & 31;
    int qi = h*131072 + n*32 + d;
    qb[qi]   = f2bf(aq * QSCALE);
    kbuf[qi] = f2bf(ak);
    vt[c*4096 + n] = f2bf(av);
}

// ---------------- K2: MFMA flash attention (unchanged) ----------------
__global__ __launch_bounds__(256) void k_attn(
    const ushort* __restrict__ qb, const ushort* __restrict__ kb,
    const ushort* __restrict__ vt, float* __restrict__ ctxT)
{
    __shared__ float mbuf[4][16];
    __shared__ float lbuf[4][16];
    __shared__ float obuf[4][512];
    int tid = threadIdx.x;
    int lane = tid & 63;
    int wv = tid >> 6;
    int h = blockIdx.x & 3;
    int qt = blockIdx.x >> 2;
    int q15 = lane & 15;
    int g = lane >> 4;
    const ushort* qhb = qb + h*131072;
    const ushort* khb = kb + h*131072;
    const ushort* vhb = vt + h*131072;
    short8v qf = *(const short8v*)(qhb + (qt*16 + q15)*32 + g*8);
    int key0off = ((q15 >> 2) << 3) + (q15 & 3);
    f32x4 o0 = {0.f,0.f,0.f,0.f}, o1 = {0.f,0.f,0.f,0.f};
    const f32x4 z = {0.f,0.f,0.f,0.f};
    float m_run = -1e30f, l_run = 0.f;
    int kstart = wv * 1024;
    for (int k32 = kstart; k32 < kstart + 1024; k32 += 32) {
        short8v kf0 = *(const short8v*)(khb + (k32 + key0off)*32 + g*8);
        short8v kf1 = *(const short8v*)(khb + (k32 + key0off + 4)*32 + g*8);
        short8v vf0 = *(const short8v*)(vhb + q15*4096 + k32 + g*8);
        short8v vf1 = *(const short8v*)(vhb + (16 + q15)*4096 + k32 + g*8);
        f32x4 s0 = __builtin_amdgcn_mfma_f32_16x16x32_bf16(kf0, qf, z, 0, 0, 0);
        f32x4 s1 = __builtin_amdgcn_mfma_f32_16x16x32_bf16(kf1, qf, z, 0, 0, 0);
        float tmax = fmaxf(fmaxf(fmaxf(s0[0], s0[1]), fmaxf(s0[2], s0[3])),
                           fmaxf(fmaxf(s1[0], s1[1]), fmaxf(s1[2], s1[3])));
        tmax = fmaxf(tmax, __shfl_xor(tmax, 16, 64));
        tmax = fmaxf(tmax, __shfl_xor(tmax, 32, 64));
        float mnew = fmaxf(m_run, tmax);
        float sc = fexp2(m_run - mnew);
        float p0 = fexp2(s0[0] - mnew), p1 = fexp2(s0[1] - mnew);
        float p2 = fexp2(s0[2] - mnew), p3 = fexp2(s0[3] - mnew);
        float p4 = fexp2(s1[0] - mnew), p5 = fexp2(s1[1] - mnew);
        float p6 = fexp2(s1[2] - mnew), p7 = fexp2(s1[3] - mnew);
        float psum = ((p0 + p1) + (p2 + p3)) + ((p4 + p5) + (p6 + p7));
        psum += __shfl_xor(psum, 16, 64);
        psum += __shfl_xor(psum, 32, 64);
        l_run = l_run * sc + psum;
        m_run = mnew;
        #pragma unroll
        for (int r = 0; r < 4; r++) { o0[r] *= sc; o1[r] *= sc; }
        short8v pf;
        pf[0] = (short)f2bf(p0); pf[1] = (short)f2bf(p1);
        pf[2] = (short)f2bf(p2); pf[3] = (short)f2bf(p3);
        pf[4] = (short)f2bf(p4); pf[5] = (short)f2bf(p5);
        pf[6] = (short)f2bf(p6); pf[7] = (short)f2bf(p7);
        o0 = __builtin_amdgcn_mfma_f32_16x16x32_bf16(vf0, pf, o0, 0, 0, 0);
        o1 = __builtin_amdgcn_mfma_f32_16x16x32_bf16(vf1, pf, o1, 0, 0, 0);
    }
    if (lane < 16) { mbuf[wv][lane] = m_run; lbuf[wv][lane] = l_run; }
    #pragma unroll
    for (int r = 0; r < 4; r++) {
        obuf[wv][r*64 + lane]       = o0[r];
        obuf[wv][(4 + r)*64 + lane] = o1[r];
    }
    __syncthreads();
    for (int e = tid; e < 512; e += 256) {
        int lp = e & 63, r8 = e >> 6;
        int q = lp & 15;
        float m0 = mbuf[0][q], m1 = mbuf[1][q], m2 = mbuf[2][q], m3 = mbuf[3][q];
        float M = fmaxf(fmaxf(m0, m1), fmaxf(m2, m3));
        float sc0 = fexp2(m0 - M), sc1 = fexp2(m1 - M);
        float sc2 = fexp2(m2 - M), sc3 = fexp2(m3 - M);
        float L = lbuf[0][q]*sc0 + lbuf[1][q]*sc1 + lbuf[2][q]*sc2 + lbuf[3][q]*sc3;
        float a = obuf[0][e]*sc0 + obuf[1][e]*sc1 + obuf[2][e]*sc2 + obuf[3][e]*sc3;
        int d = ((lp >> 4) << 2) + (r8 & 3) + ((r8 >> 2) << 4);
        ctxT[(h*32 + d)*4096 + qt*16 + q] = a / L;
    }
}

// ---------------- K3: attn_out + outp with transposed weights ----------------
__global__ __launch_bounds__(128) void k_out_base(
    const float* __restrict__ ctxT, const float* __restrict__ wt,
    const float* __restrict__ ab, const float* __restrict__ ob,
    float* __restrict__ base)
{
    __shared__ float cs[128];
    __shared__ float as[128];
    int n = blockIdx.x, c = threadIdx.x;
    cs[c] = ctxT[c*4096 + n];
    __syncthreads();
    float acc = ab[c];
    const float* awT = wt + T_AW;
    #pragma unroll 8
    for (int i = 0; i < 128; i++) acc += cs[i]*awT[i*128 + c];
    as[c] = acc;
    __syncthreads();
    float acc2 = ob[c];
    const float* owT = wt + T_OW;
    #pragma unroll 8
    for (int i = 0; i < 128; i++) acc2 += as[i]*owT[i*128 + c];
    base[n*128+c] = acc2;
}

// ---------------- K6a: per-node sc-MLP x partials (coalesced) ----------------
__global__ __launch_bounds__(128) void k_node_sc(
    const float* __restrict__ x, const float* __restrict__ wt,
    float* __restrict__ xsa, float* __restrict__ xtb)
{
    __shared__ float xs[128];
    int n = blockIdx.x, c = threadIdx.x;
    xs[c] = x[n*128+c];
    __syncthreads();
    const float* scT = wt + T_SC;
    float acc = 0.f;
    #pragma unroll 8
    for (int i = 0; i < 128; i++) acc += xs[i]*scT[i*128 + c];
    if (c < 64) xsa[n*64+c] = acc; else xtb[n*64+(c-64)] = acc;
}

// ---------------- K4: per-edge slots ----------------
__global__ __launch_bounds__(256) void k_fill(
    const int* __restrict__ eidx, int* __restrict__ cnt_s, int* __restrict__ cnt_t,
    int* __restrict__ slot_s, int* __restrict__ slot_t)
{
    int e = blockIdx.x*256 + threadIdx.x;
    int s = eidx[e], t = eidx[N_EDGES + e];
    slot_s[e] = atomicAdd(&cnt_s[s], 1);
    slot_t[e] = atomicAdd(&cnt_t[t], 1);
}

// ---------------- K6: per-edge PWL -> packed records ----------------
__global__ __launch_bounds__(256) void k_edge(
    const int* __restrict__ eidx, const float* __restrict__ etime,
    const float* __restrict__ eattr,
    const float* __restrict__ tab, const float* __restrict__ aux,
    const float* __restrict__ sc_b1, const float* __restrict__ sc_w2,
    const float* __restrict__ sc_b2, const float* __restrict__ decay_p,
    const float* __restrict__ xsa, const float* __restrict__ xtb,
    const int* __restrict__ slot_s, const int* __restrict__ slot_t,
    float4* __restrict__ recS, float2* __restrict__ recT, float* __restrict__ nscore)
{
    int tid = threadIdx.x;
    int lane = tid & 63;
    int wv = tid >> 6;
    float thr = 0.f;
    if (lane < 32) thr = aux[lane];
    float R0  = aux[32 + lane];
    float sb1 = sc_b1[lane], sw2 = sc_w2[lane];
    float decay = decay_p[0];
    float sb2 = sc_b2[0];
    for (int base_e = blockIdx.x*8; base_e < N_EDGES; base_e += 2048*8) {
        #pragma unroll
        for (int ii = 0; ii < 2; ii++) {
            int e = base_e + wv + ii*4;
            int src = eidx[e];
            int tgt = eidx[N_EDGES + e];
            float t = etime[e];
            float wt = t * __expf(-fabsf(t)*decay);
            bool pr = (lane < 32) && (wt > thr);
            int r = __popcll(__ballot(pr));
            const float* row = tab + r*320;
            float P  = row[128+lane], Q = row[192+lane];
            float qa = row[256], qb = row[257], qc = row[258];
            float isd = rsqrtf(fmaf(fmaf(qa, wt, qb), wt, qc) + EPS);
            float u = sb1 + xsa[src*64 + lane] + xtb[tgt*64 + lane] + R0;
            float rh = fmaxf(fmaf(isd, fmaf(P, wt, Q), u), 0.f);
            float ps = rh * sw2;
            #pragma unroll
            for (int m = 32; m >= 1; m >>= 1) ps += __shfl_xor(ps, m, 64);
            float score = 1.f / (1.f + __expf(-(ps + sb2)));
            if (lane == 0) {
                atomicAdd(&nscore[src], score);
                float hier = eattr[e*17 + 16];
                float tfj  = eattr[e*17 + 5];
                float wf = 0.f, wr2 = 0.f;
                if (hier > 0.f) {
                    wf  = hier * (1.f/(1.f + __expf(-tfj))) * 0.3f;
                    wr2 = hier * 0.1f;
                }
                int ps_ = slot_s[e], pt_ = slot_t[e];
                if (ps_ < CAP) {
                    float4 rv;
                    rv.x = __builtin_bit_cast(float, (uint)(tgt | (r << 12)));
                    rv.y = wf;
                    rv.z = score * isd * wt;
                    rv.w = score * isd;
                    recS[src*CAP + ps_] = rv;
                }
                if (pt_ < CAP)
                    recT[tgt*CAP + pt_] = make_float2(__builtin_bit_cast(float, (uint)src), wr2);
            }
        }
    }
}

// ---------------- K7: LDS-staged gather + agg GEMM + LN + relu ----------------
__global__ __launch_bounds__(256) void k_final(
    const float* __restrict__ base, const float4* __restrict__ recS,
    const float2* __restrict__ recT, const int* __restrict__ cnt_s,
    const int* __restrict__ cnt_t, const float* __restrict__ nscore,
    const float* __restrict__ tab, const float* __restrict__ ln_b,
    const float* __restrict__ wt, const float* __restrict__ agg_b,
    const float* __restrict__ g, const float* __restrict__ b, float* __restrict__ out)
{
    __shared__ float agbg[33*128];
    __shared__ int   sIdx[CAP];
    __shared__ float sWf[CAP], sZ[CAP], sWc[CAP];
    __shared__ int   tIdx[CAP];
    __shared__ float tWr[CAP];
    __shared__ float partial[2][128];
    __shared__ float partialN[4][64];
    __shared__ float comb[192];
    __shared__ float red[8];
    int n = blockIdx.x, tid = threadIdx.x;
    for (int i = tid; i < 33*128; i += 256)
        agbg[i] = tab[(i >> 7)*320 + (i & 127)];
    int ns = min(cnt_s[n], CAP);
    int nt = min(cnt_t[n], CAP);
    const float4* rs = recS + n*CAP;
    const float2* rt = recT + n*CAP;
    for (int i = tid; i < ns; i += 256) {
        float4 r = rs[i];
        sIdx[i] = (int)__builtin_bit_cast(uint, r.x);
        sWf[i] = r.y; sZ[i] = r.z; sWc[i] = r.w;
    }
    for (int i = tid; i < nt; i += 256) {
        float2 r = rt[i];
        tIdx[i] = (int)__builtin_bit_cast(uint, r.x);
        tWr[i] = r.y;
    }
    __syncthreads();
    // Phase B: base-row gather, 2-way split per channel, indices from LDS
    {
        int c = tid & 127, half = tid >> 7;
        float acc = 0.f;
        for (int i = half; i < ns; i += 2)
            acc = fmaf(base[(sIdx[i] & 4095)*128 + c], sWf[i], acc);
        for (int i = half; i < nt; i += 2)
            acc = fmaf(base[tIdx[i]*128 + c], tWr[i], acc);
        partial[half][c] = acc;
    }
    // Phase C: nctx from region table, 4-way split
    {
        int c2 = tid & 63, q = tid >> 6;
        float accn = 0.f;
        for (int i = q; i < ns; i += 4) {
            int v = sIdx[i];
            int rg = (v >> 12) & 63;
            accn = fmaf(sZ[i], agbg[rg*128 + c2], fmaf(sWc[i], agbg[rg*128 + 64 + c2], accn));
        }
        partialN[q][c2] = accn;
    }
    __syncthreads();
    if (tid < 128) {
        comb[tid] = base[n*128 + tid] + partial[0][tid] + partial[1][tid];
    } else if (tid < 192) {
        int c3 = tid - 128;
        comb[tid] = partialN[0][c3] + partialN[1][c3] + partialN[2][c3] + partialN[3][c3]
                  + nscore[n]*ln_b[c3];
    }
    __syncthreads();
    int c = tid;
    float acc = agg_b[c];
    const float* aggT = wt + T_AGG;
    #pragma unroll 4
    for (int i = 0; i < 192; i++) acc += comb[i]*aggT[i*256 + c];
    int lane = c & 63, w = c >> 6;
    float s = acc;
    #pragma unroll
    for (int m = 32; m >= 1; m >>= 1) s += __shfl_xor(s, m, 64);
    if (lane == 0) red[w] = s;
    __syncthreads();
    float mu = (red[0]+red[1]+red[2]+red[3]) * (1.f/256.f);
    float d = acc - mu;
    float s2 = d*d;
    #pragma unroll
    for (int m = 32; m >= 1; m >>= 1) s2 += __shfl_xor(s2, m, 64);
    if (lane == 0) red[4+w] = s2;
    __syncthreads();
    float var = (red[4]+red[5]+red[6]+red[7]) * (1.f/256.f);
    float y = d * rsqrtf(var + EPS) * g[c] + b[c];
    out[n*256+c] = fmaxf(y, 0.f);
}

extern "C" void kernel_launch(void* const* d_in, const int* in_sizes, int n_in,
                              void* d_out, int out_size, void* d_ws, size_t ws_size,
                              hipStream_t stream)
{
    const float* x        = (const float*)d_in[0];
    const int*   eidx     = (const int*)d_in[1];
    const float* etime    = (const float*)d_in[2];
    const float* eattr    = (const float*)d_in[3];
    const float* te_w1    = (const float*)d_in[4];
    const float* te_b1    = (const float*)d_in[5];
    const float* te_w2    = (const float*)d_in[6];
    const float* te_b2    = (const float*)d_in[7];
    const float* te_ln_g  = (const float*)d_in[8];
    const float* te_ln_b  = (const float*)d_in[9];
    const float* inp_w    = (const float*)d_in[10];
    const float* inp_b    = (const float*)d_in[11];
    const float* wq       = (const float*)d_in[12];
    const float* bq       = (const float*)d_in[13];
    const float* wk       = (const float*)d_in[14];
    const float* bk       = (const float*)d_in[15];
    const float* wv       = (const float*)d_in[16];
    const float* bv       = (const float*)d_in[17];
    const float* aow      = (const float*)d_in[18];
    const float* aob      = (const float*)d_in[19];
    const float* ow       = (const float*)d_in[20];
    const float* ob       = (const float*)d_in[21];
    const float* sc_w1    = (const float*)d_in[22];
    const float* sc_b1    = (const float*)d_in[23];
    const float* sc_w2    = (const float*)d_in[24];
    const float* sc_b2    = (const float*)d_in[25];
    const float* agg_w    = (const float*)d_in[26];
    const float* agg_b    = (const float*)d_in[27];
    const float* agg_g    = (const float*)d_in[28];
    const float* agg_bb   = (const float*)d_in[29];
    const float* decay    = (const float*)d_in[30];
    float* ws = (float*)d_ws;
    float* out = (float*)d_out;
    ushort* qb   = (ushort*)(ws + O_QB);
    ushort* kbuf = (ushort*)(ws + O_KB);
    ushort* vt   = (ushort*)(ws + O_VT);
    float4* recS = (float4*)(ws + O_RECS);
    float2* recT = (float2*)(ws + O_RECT);
    int* slot_s  = (int*)(ws + O_SLS);
    int* slot_t  = (int*)(ws + O_SLT);
    int* cnt_s   = (int*)(ws + O_CNTS);
    int* cnt_t   = (int*)(ws + O_CNTT);
    float* nscore = ws + O_NSC;
    float* wtb   = ws + O_WT;

    hipMemsetAsync(ws + O_CNTS, 0, 12288*sizeof(int), stream);

    k_tr<<<640, 256, 0, stream>>>(inp_w, wq, wk, wv, aow, ow, sc_w1, agg_w, wtb);
    k_setup<<<33, 64, 0, stream>>>(te_w1, te_b1, te_w2, te_b2, te_ln_g, te_ln_b,
                                   sc_w1, ws+O_TAB, ws+O_AUX);
    k_proj_qkv<<<N_NODES, 128, 0, stream>>>(x, wtb, inp_b, bq, bk, bv, qb, kbuf, vt);
    k_node_sc<<<N_NODES, 128, 0, stream>>>(x, wtb, ws+O_XSA, ws+O_XTB);
    k_fill<<<N_EDGES/256, 256, 0, stream>>>(eidx, cnt_s, cnt_t, slot_s, slot_t);
    k_edge<<<2048, 256, 0, stream>>>(eidx, etime, eattr, ws+O_TAB, ws+O_AUX,
                                     sc_b1, sc_w2, sc_b2, decay,
                                     ws+O_XSA, ws+O_XTB, slot_s, slot_t,
                                     recS, recT, nscore);
    k_attn<<<1024, 256, 0, stream>>>(qb, kbuf, vt, ws+O_CTXT);
    k_out_base<<<N_NODES, 128, 0, stream>>>(ws+O_CTXT, wtb, aob, ob, ws+O_BASE);
    k_final<<<N_NODES, 256, 0, stream>>>(ws+O_BASE, recS, recT, cnt_s, cnt_t, nscore,
                                         ws+O_TAB, te_ln_b, wtb,
                                         agg_b, agg_g, agg_bb, out);
}

// Round 6
// 273.691 us; speedup vs baseline: 4.3881x; 1.1758x over previous
//
#include <hip/hip_runtime.h>

#define N_NODES 4096
#define N_EDGES 262144
#define EPS 1e-5f
#define CAP 192

// workspace offsets (float units)
#define O_CTXT 0        // ctx^T f32 [128][4096]
#define O_BASE 524288   // base [4096][128]
#define O_XSA  1048576
#define O_XTB  1310720
#define O_TAB  1572864  // 33 regions x 320
#define O_AUX  1583424  // thr[32] + R0[64]
#define O_RECS 1583552  // float4 [4096][CAP]
#define O_RECT 4729280  // float2 [4096][CAP]
#define O_SLS  6302144  // int[E] slot in src list
#define O_WFS  6564288  // float[E] wf
#define O_CNTS 6826432
#define O_CNTT 6830528
#define O_NSC  6834624
#define O_QB   6838720  // bf16 [4][4096][32]
#define O_KB   7100864
#define O_VT   7363008  // bf16 [4][32][4096]
#define O_WT   7625152  // transposed weights
#define O_CMB  7788992  // comb [4096][192]
// within WT:
#define T_INP  0
#define T_WQ   16384
#define T_WK   32768
#define T_WV   49152
#define T_AW   65536
#define T_OW   81920
#define T_SC   98304
#define T_AGG  114688   // [192][256]

typedef __attribute__((ext_vector_type(8))) short short8v;
typedef __attribute__((ext_vector_type(4))) float f32x4;

__device__ __forceinline__ ushort f2bf(float x) {
    uint u = __builtin_bit_cast(uint, x);
    uint r = (u + 0x7FFFu + ((u >> 16) & 1u)) >> 16;
    return (ushort)r;
}
__device__ __forceinline__ float fexp2(float x) { return __builtin_amdgcn_exp2f(x); }

// ---------------- K-1: one-time weight transposes ----------------
__global__ __launch_bounds__(256) void k_tr(
    const float* __restrict__ inp_w, const float* __restrict__ wq,
    const float* __restrict__ wk, const float* __restrict__ wv,
    const float* __restrict__ aw, const float* __restrict__ ow,
    const float* __restrict__ sc_w1, const float* __restrict__ agg_w,
    float* __restrict__ wt)
{
    int idx = blockIdx.x*256 + threadIdx.x;
    if (idx < 114688) {
        int m = idx >> 14;
        int r = idx & 16383;
        int i = r >> 7, c = r & 127;
        float v;
        switch (m) {
            case 0: v = inp_w[c*128+i]; break;
            case 1: v = wq[c*128+i]; break;
            case 2: v = wk[c*128+i]; break;
            case 3: v = wv[c*128+i]; break;
            case 4: v = aw[c*128+i]; break;
            case 5: v = ow[c*128+i]; break;
            default: v = (c < 64) ? sc_w1[c*320+i] : sc_w1[(c-64)*320+128+i]; break;
        }
        wt[idx] = v;
    } else {
        int a = idx - 114688;
        int i = a >> 8, c = a & 255;
        wt[idx] = agg_w[c*192 + i];
    }
}

// ---------------- K0: region tables for piecewise-linear temporal MLP ----------------
__global__ __launch_bounds__(64) void k_setup(
    const float* __restrict__ te_w1, const float* __restrict__ te_b1,
    const float* __restrict__ te_w2, const float* __restrict__ te_b2,
    const float* __restrict__ ln_g, const float* __restrict__ ln_b,
    const float* __restrict__ sc_w1, float* __restrict__ tab, float* __restrict__ aux)
{
    __shared__ float t_s[32];
    __shared__ int pos_s[32];
    __shared__ float AG_s[64], BG_s[64];
    int r = blockIdx.x;
    int c = threadIdx.x;
    if (c < 32) {
        float w = te_w1[c], b = te_b1[c];
        t_s[c] = (w != 0.f) ? (-b / w) : 1e30f;
    }
    __syncthreads();
    if (c < 32) {
        float t = t_s[c];
        int p = 0;
        for (int i = 0; i < 32; i++) {
            float ti = t_s[i];
            p += (ti < t) || (ti == t && i < c);
        }
        pos_s[c] = p;
    }
    __syncthreads();
    float A = 0.f, B = te_b2[c];
    for (int j = 0; j < 32; j++) {
        float w = te_w1[j], b = te_b1[j];
        bool act = (w > 0.f) ? (pos_s[j] < r) : ((w < 0.f) ? (pos_s[j] >= r) : (b > 0.f));
        if (act) { float w2 = te_w2[c*32 + j]; A += w * w2; B += b * w2; }
    }
    float mA = A, mB = B;
    #pragma unroll
    for (int m = 32; m >= 1; m >>= 1) { mA += __shfl_xor(mA, m, 64); mB += __shfl_xor(mB, m, 64); }
    mA *= (1.f/64.f); mB *= (1.f/64.f);
    float a = A - mA, bq = B - mB;
    float qa = a*a, qb = a*bq, qc = bq*bq;
    #pragma unroll
    for (int m = 32; m >= 1; m >>= 1) {
        qa += __shfl_xor(qa, m, 64); qb += __shfl_xor(qb, m, 64); qc += __shfl_xor(qc, m, 64);
    }
    qa *= (1.f/64.f); qb *= (2.f/64.f); qc *= (1.f/64.f);
    float g = ln_g[c];
    float AG = a*g, BG = bq*g;
    AG_s[c] = AG; BG_s[c] = BG;
    float* row = tab + r*320;
    row[c] = AG; row[64+c] = BG;
    if (c == 0) { row[256] = qa; row[257] = qb; row[258] = qc; }
    __syncthreads();
    const float* wc = sc_w1 + c*320 + 256;
    float P = 0.f, Q = 0.f;
    for (int j = 0; j < 64; j++) { float w = wc[j]; P += AG_s[j]*w; Q += BG_s[j]*w; }
    row[128+c] = P; row[192+c] = Q;
    if (r == 0) {
        if (c < 32) aux[pos_s[c]] = t_s[c];
        float R0 = 0.f;
        for (int j = 0; j < 64; j++) R0 += ln_b[j] * wc[j];
        aux[32 + c] = R0;
    }
}

// ---------------- K1: projections, 4 nodes/block ----------------
__global__ __launch_bounds__(128) void k_proj_qkv(
    const float* __restrict__ x, const float* __restrict__ wt,
    const float* __restrict__ inp_b,
    const float* __restrict__ bq, const float* __restrict__ bk, const float* __restrict__ bv,
    ushort* __restrict__ qb, ushort* __restrict__ kbuf, ushort* __restrict__ vt)
{
    __shared__ float xs[512];
    __shared__ float xps[4][128];
    int n0 = blockIdx.x*4;
    int c = threadIdx.x;
    for (int i = c; i < 512; i += 128) xs[i] = x[n0*128 + i];
    __syncthreads();
    const float* inpT = wt + T_INP;
    float ib = inp_b[c];
    float a0 = ib, a1 = ib, a2 = ib, a3 = ib;
    #pragma unroll 4
    for (int i = 0; i < 128; i++) {
        float w = inpT[i*128 + c];
        a0 = fmaf(xs[i], w, a0);
        a1 = fmaf(xs[128+i], w, a1);
        a2 = fmaf(xs[256+i], w, a2);
        a3 = fmaf(xs[384+i], w, a3);
    }
    xps[0][c] = a0; xps[1][c] = a1; xps[2][c] = a2; xps[3][c] = a3;
    __syncthreads();
    float bqc = bq[c], bkc = bk[c], bvc = bv[c];
    float q0=bqc,q1=bqc,q2=bqc,q3=bqc;
    float k0=bkc,k1=bkc,k2=bkc,k3=bkc;
    float v0=bvc,v1=bvc,v2=bvc,v3=bvc;
    const float* wqT = wt + T_WQ;
    const float* wkT = wt + T_WK;
    const float* wvT = wt + T_WV;
    #pragma unroll 2
    for (int i = 0; i < 128; i++) {
        float wQ = wqT[i*128 + c], wK = wkT[i*128 + c], wV = wvT[i*128 + c];
        float x0 = xps[0][i], x1 = xps[1][i], x2 = xps[2][i], x3 = xps[3][i];
        q0=fmaf(x0,wQ,q0); q1=fmaf(x1,wQ,q1); q2=fmaf(x2,wQ,q2); q3=fmaf(x3,wQ,q3);
        k0=fmaf(x0,wK,k0); k1=fmaf(x1,wK,k1); k2=fmaf(x2,wK,k2); k3=fmaf(x3,wK,k3);
        v0=fmaf(x0,wV,v0); v1=fmaf(x1,wV,v1); v2=fmaf(x2,wV,v2); v3=fmaf(x3,wV,v3);
    }
    const float QSCALE = 0.17677669529663687f * 1.4426950408889634f;
    int h = c >> 5, d = c & 31;
    float qa_[4] = {q0,q1,q2,q3};
    float ka_[4] = {k0,k1,k2,k3};
    float va_[4] = {v0,v1,v2,v3};
    #pragma unroll
    for (int j = 0; j < 4; j++) {
        int n = n0 + j;
        int qi = h*131072 + n*32 + d;
        qb[qi]   = f2bf(qa_[j] * QSCALE);
        kbuf[qi] = f2bf(ka_[j]);
        vt[c*4096 + n] = f2bf(va_[j]);
    }
}

// ---------------- K2: MFMA flash attention (unchanged) ----------------
__global__ __launch_bounds__(256) void k_attn(
    const ushort* __restrict__ qb, const ushort* __restrict__ kb,
    const ushort* __restrict__ vt, float* __restrict__ ctxT)
{
    __shared__ float mbuf[4][16];
    __shared__ float lbuf[4][16];
    __shared__ float obuf[4][512];
    int tid = threadIdx.x;
    int lane = tid & 63;
    int wv = tid >> 6;
    int h = blockIdx.x & 3;
    int qt = blockIdx.x >> 2;
    int q15 = lane & 15;
    int g = lane >> 4;
    const ushort* qhb = qb + h*131072;
    const ushort* khb = kb + h*131072;
    const ushort* vhb = vt + h*131072;
    short8v qf = *(const short8v*)(qhb + (qt*16 + q15)*32 + g*8);
    int key0off = ((q15 >> 2) << 3) + (q15 & 3);
    f32x4 o0 = {0.f,0.f,0.f,0.f}, o1 = {0.f,0.f,0.f,0.f};
    const f32x4 z = {0.f,0.f,0.f,0.f};
    float m_run = -1e30f, l_run = 0.f;
    int kstart = wv * 1024;
    for (int k32 = kstart; k32 < kstart + 1024; k32 += 32) {
        short8v kf0 = *(const short8v*)(khb + (k32 + key0off)*32 + g*8);
        short8v kf1 = *(const short8v*)(khb + (k32 + key0off + 4)*32 + g*8);
        short8v vf0 = *(const short8v*)(vhb + q15*4096 + k32 + g*8);
        short8v vf1 = *(const short8v*)(vhb + (16 + q15)*4096 + k32 + g*8);
        f32x4 s0 = __builtin_amdgcn_mfma_f32_16x16x32_bf16(kf0, qf, z, 0, 0, 0);
        f32x4 s1 = __builtin_amdgcn_mfma_f32_16x16x32_bf16(kf1, qf, z, 0, 0, 0);
        float tmax = fmaxf(fmaxf(fmaxf(s0[0], s0[1]), fmaxf(s0[2], s0[3])),
                           fmaxf(fmaxf(s1[0], s1[1]), fmaxf(s1[2], s1[3])));
        tmax = fmaxf(tmax, __shfl_xor(tmax, 16, 64));
        tmax = fmaxf(tmax, __shfl_xor(tmax, 32, 64));
        float mnew = fmaxf(m_run, tmax);
        float sc = fexp2(m_run - mnew);
        float p0 = fexp2(s0[0] - mnew), p1 = fexp2(s0[1] - mnew);
        float p2 = fexp2(s0[2] - mnew), p3 = fexp2(s0[3] - mnew);
        float p4 = fexp2(s1[0] - mnew), p5 = fexp2(s1[1] - mnew);
        float p6 = fexp2(s1[2] - mnew), p7 = fexp2(s1[3] - mnew);
        float psum = ((p0 + p1) + (p2 + p3)) + ((p4 + p5) + (p6 + p7));
        psum += __shfl_xor(psum, 16, 64);
        psum += __shfl_xor(psum, 32, 64);
        l_run = l_run * sc + psum;
        m_run = mnew;
        #pragma unroll
        for (int r = 0; r < 4; r++) { o0[r] *= sc; o1[r] *= sc; }
        short8v pf;
        pf[0] = (short)f2bf(p0); pf[1] = (short)f2bf(p1);
        pf[2] = (short)f2bf(p2); pf[3] = (short)f2bf(p3);
        pf[4] = (short)f2bf(p4); pf[5] = (short)f2bf(p5);
        pf[6] = (short)f2bf(p6); pf[7] = (short)f2bf(p7);
        o0 = __builtin_amdgcn_mfma_f32_16x16x32_bf16(vf0, pf, o0, 0, 0, 0);
        o1 = __builtin_amdgcn_mfma_f32_16x16x32_bf16(vf1, pf, o1, 0, 0, 0);
    }
    if (lane < 16) { mbuf[wv][lane] = m_run; lbuf[wv][lane] = l_run; }
    #pragma unroll
    for (int r = 0; r < 4; r++) {
        obuf[wv][r*64 + lane]       = o0[r];
        obuf[wv][(4 + r)*64 + lane] = o1[r];
    }
    __syncthreads();
    for (int e = tid; e < 512; e += 256) {
        int lp = e & 63, r8 = e >> 6;
        int q = lp & 15;
        float m0 = mbuf[0][q], m1 = mbuf[1][q], m2 = mbuf[2][q], m3 = mbuf[3][q];
        float M = fmaxf(fmaxf(m0, m1), fmaxf(m2, m3));
        float sc0 = fexp2(m0 - M), sc1 = fexp2(m1 - M);
        float sc2 = fexp2(m2 - M), sc3 = fexp2(m3 - M);
        float L = lbuf[0][q]*sc0 + lbuf[1][q]*sc1 + lbuf[2][q]*sc2 + lbuf[3][q]*sc3;
        float a = obuf[0][e]*sc0 + obuf[1][e]*sc1 + obuf[2][e]*sc2 + obuf[3][e]*sc3;
        int d = ((lp >> 4) << 2) + (r8 & 3) + ((r8 >> 2) << 4);
        ctxT[(h*32 + d)*4096 + qt*16 + q] = a / L;
    }
}

// ---------------- K3: attn_out + outp, 4 nodes/block ----------------
__global__ __launch_bounds__(128) void k_out_base(
    const float* __restrict__ ctxT, const float* __restrict__ wt,
    const float* __restrict__ ab, const float* __restrict__ ob,
    float* __restrict__ base)
{
    __shared__ float cs[4][128];
    __shared__ float as[4][128];
    int n0 = blockIdx.x*4;
    int c = threadIdx.x;
    float4 cv = *(const float4*)(ctxT + c*4096 + n0);
    cs[0][c] = cv.x; cs[1][c] = cv.y; cs[2][c] = cv.z; cs[3][c] = cv.w;
    __syncthreads();
    float abc = ab[c];
    float a0=abc,a1=abc,a2=abc,a3=abc;
    const float* awT = wt + T_AW;
    #pragma unroll 4
    for (int i = 0; i < 128; i++) {
        float w = awT[i*128 + c];
        a0=fmaf(cs[0][i],w,a0); a1=fmaf(cs[1][i],w,a1);
        a2=fmaf(cs[2][i],w,a2); a3=fmaf(cs[3][i],w,a3);
    }
    as[0][c]=a0; as[1][c]=a1; as[2][c]=a2; as[3][c]=a3;
    __syncthreads();
    float obc = ob[c];
    float b0=obc,b1=obc,b2=obc,b3=obc;
    const float* owT = wt + T_OW;
    #pragma unroll 4
    for (int i = 0; i < 128; i++) {
        float w = owT[i*128 + c];
        b0=fmaf(as[0][i],w,b0); b1=fmaf(as[1][i],w,b1);
        b2=fmaf(as[2][i],w,b2); b3=fmaf(as[3][i],w,b3);
    }
    base[(n0+0)*128+c]=b0; base[(n0+1)*128+c]=b1;
    base[(n0+2)*128+c]=b2; base[(n0+3)*128+c]=b3;
}

// ---------------- K6a: per-node sc-MLP x partials, 4 nodes/block ----------------
__global__ __launch_bounds__(128) void k_node_sc(
    const float* __restrict__ x, const float* __restrict__ wt,
    float* __restrict__ xsa, float* __restrict__ xtb)
{
    __shared__ float xs[512];
    int n0 = blockIdx.x*4;
    int c = threadIdx.x;
    for (int i = c; i < 512; i += 128) xs[i] = x[n0*128 + i];
    __syncthreads();
    const float* scT = wt + T_SC;
    float a0=0,a1=0,a2=0,a3=0;
    #pragma unroll 4
    for (int i = 0; i < 128; i++) {
        float w = scT[i*128 + c];
        a0=fmaf(xs[i],w,a0); a1=fmaf(xs[128+i],w,a1);
        a2=fmaf(xs[256+i],w,a2); a3=fmaf(xs[384+i],w,a3);
    }
    float av[4] = {a0,a1,a2,a3};
    #pragma unroll
    for (int j = 0; j < 4; j++) {
        int n = n0 + j;
        if (c < 64) xsa[n*64+c] = av[j]; else xtb[n*64+(c-64)] = av[j];
    }
}

// ---------------- K4: slots + eattr extraction + recT ----------------
__global__ __launch_bounds__(256) void k_fill(
    const int* __restrict__ eidx, const float* __restrict__ eattr,
    int* __restrict__ cnt_s, int* __restrict__ cnt_t,
    int* __restrict__ slot_s, float* __restrict__ wfS, float2* __restrict__ recT)
{
    int e = blockIdx.x*256 + threadIdx.x;
    int s = eidx[e], t = eidx[N_EDGES + e];
    float hier = eattr[e*17 + 16];
    float tfj  = eattr[e*17 + 5];
    float wf = 0.f, wr = 0.f;
    if (hier > 0.f) {
        wf = hier * (1.f/(1.f + __expf(-tfj))) * 0.3f;
        wr = hier * 0.1f;
    }
    slot_s[e] = atomicAdd(&cnt_s[s], 1);
    wfS[e] = wf;
    int pt = atomicAdd(&cnt_t[t], 1);
    if (pt < CAP)
        recT[t*CAP + pt] = make_float2(__builtin_bit_cast(float, (uint)s), wr);
}

// ---------------- K6: per-edge PWL -> packed records (ILP-4, LDS tables) ----------------
__global__ __launch_bounds__(256) void k_edge(
    const int* __restrict__ eidx, const float* __restrict__ etime,
    const float* __restrict__ tab, const float* __restrict__ aux,
    const float* __restrict__ sc_b1, const float* __restrict__ sc_w2,
    const float* __restrict__ sc_b2, const float* __restrict__ decay_p,
    const float* __restrict__ xsa, const float* __restrict__ xtb,
    const int* __restrict__ slot_s, const float* __restrict__ wfS,
    float4* __restrict__ recS, float* __restrict__ nscore)
{
    __shared__ float pq[33*128];    // [r][0..63]=P, [r][64..127]=Q
    __shared__ float qpoly[33*4];
    int tid = threadIdx.x;
    for (int i = tid; i < 33*128; i += 256)
        pq[i] = tab[(i >> 7)*320 + 128 + (i & 127)];
    if (tid < 33) {
        qpoly[tid*4+0] = tab[tid*320+256];
        qpoly[tid*4+1] = tab[tid*320+257];
        qpoly[tid*4+2] = tab[tid*320+258];
    }
    int lane = tid & 63;
    int wv = tid >> 6;
    float thr = 0.f;
    if (lane < 32) thr = aux[lane];
    float R0  = aux[32 + lane];
    float sb1 = sc_b1[lane], sw2 = sc_w2[lane];
    float decay = decay_p[0];
    float sb2 = sc_b2[0];
    __syncthreads();
    for (int base_e = blockIdx.x*16; base_e < N_EDGES; base_e += 2048*16) {
        #pragma unroll
        for (int ii = 0; ii < 4; ii++) {
            int e = base_e + wv + ii*4;
            int src = eidx[e];
            int tgt = eidx[N_EDGES + e];
            float t = etime[e];
            float wt = t * __expf(-fabsf(t)*decay);
            bool pr = (lane < 32) && (wt > thr);
            int r = __popcll(__ballot(pr));
            float P = pq[r*128 + lane], Q = pq[r*128 + 64 + lane];
            float qa = qpoly[r*4], qb = qpoly[r*4+1], qc = qpoly[r*4+2];
            float isd = rsqrtf(fmaf(fmaf(qa, wt, qb), wt, qc) + EPS);
            float u = sb1 + xsa[src*64 + lane] + xtb[tgt*64 + lane] + R0;
            float rh = fmaxf(fmaf(isd, fmaf(P, wt, Q), u), 0.f);
            float ps = rh * sw2;
            #pragma unroll
            for (int m = 32; m >= 1; m >>= 1) ps += __shfl_xor(ps, m, 64);
            float score = 1.f / (1.f + __expf(-(ps + sb2)));
            if (lane == 0) {
                atomicAdd(&nscore[src], score);
                int ps_ = slot_s[e];
                if (ps_ < CAP) {
                    float4 rv;
                    rv.x = __builtin_bit_cast(float, (uint)(tgt | (r << 12)));
                    rv.y = wfS[e];
                    rv.z = score * isd * wt;
                    rv.w = score * isd;
                    recS[src*CAP + ps_] = rv;
                }
            }
        }
    }
}

// ---------------- K7a: gather upd + nctx -> comb[n][192] ----------------
__global__ __launch_bounds__(256) void k_gather(
    const float* __restrict__ base, const float4* __restrict__ recS,
    const float2* __restrict__ recT, const int* __restrict__ cnt_s,
    const int* __restrict__ cnt_t, const float* __restrict__ nscore,
    const float* __restrict__ tab, const float* __restrict__ ln_b,
    float* __restrict__ comb)
{
    __shared__ int   sIdx[CAP];
    __shared__ float sWf[CAP], sZ[CAP], sWc[CAP];
    __shared__ int   tIdx[CAP];
    __shared__ float tWr[CAP];
    __shared__ float zsum[33], wsum[33];
    __shared__ float partial[2][128];
    int n = blockIdx.x, tid = threadIdx.x;
    int ns = min(cnt_s[n], CAP);
    int nt = min(cnt_t[n], CAP);
    int nsp = (ns + 7) & ~7;
    int ntp = (nt + 7) & ~7;
    const float4* rs = recS + n*CAP;
    const float2* rt = recT + n*CAP;
    if (tid < 33) { zsum[tid] = 0.f; wsum[tid] = 0.f; }
    for (int i = tid; i < nsp; i += 256) {
        if (i < ns) {
            float4 r = rs[i];
            sIdx[i] = (int)__builtin_bit_cast(uint, r.x);
            sWf[i] = r.y; sZ[i] = r.z; sWc[i] = r.w;
        } else { sIdx[i] = n; sWf[i] = 0.f; sZ[i] = 0.f; sWc[i] = 0.f; }
    }
    for (int i = tid; i < ntp; i += 256) {
        if (i < nt) {
            float2 r = rt[i];
            tIdx[i] = (int)__builtin_bit_cast(uint, r.x);
            tWr[i] = r.y;
        } else { tIdx[i] = n; tWr[i] = 0.f; }
    }
    __syncthreads();
    // per-region sums for nctx
    for (int i = tid; i < ns; i += 256) {
        int rg = (sIdx[i] >> 12) & 63;
        atomicAdd(&zsum[rg], sZ[i]);
        atomicAdd(&wsum[rg], sWc[i]);
    }
    // base-row gather, 2 halves, 4 loads in flight
    {
        int c = tid & 127, half = tid >> 7;
        float a0=0.f,a1=0.f,a2=0.f,a3=0.f;
        for (int i = half*4; i < nsp; i += 8) {
            a0 = fmaf(base[(sIdx[i+0] & 4095)*128 + c], sWf[i+0], a0);
            a1 = fmaf(base[(sIdx[i+1] & 4095)*128 + c], sWf[i+1], a1);
            a2 = fmaf(base[(sIdx[i+2] & 4095)*128 + c], sWf[i+2], a2);
            a3 = fmaf(base[(sIdx[i+3] & 4095)*128 + c], sWf[i+3], a3);
        }
        for (int i = half*4; i < ntp; i += 8) {
            a0 = fmaf(base[tIdx[i+0]*128 + c], tWr[i+0], a0);
            a1 = fmaf(base[tIdx[i+1]*128 + c], tWr[i+1], a1);
            a2 = fmaf(base[tIdx[i+2]*128 + c], tWr[i+2], a2);
            a3 = fmaf(base[tIdx[i+3]*128 + c], tWr[i+3], a3);
        }
        partial[half][c] = (a0+a1)+(a2+a3);
    }
    __syncthreads();
    if (tid < 128) {
        comb[n*192 + tid] = base[n*128 + tid] + partial[0][tid] + partial[1][tid];
    } else if (tid < 192) {
        int c3 = tid - 128;
        float acc = nscore[n]*ln_b[c3];
        #pragma unroll
        for (int r = 0; r < 33; r++)
            acc += zsum[r]*tab[r*320 + c3] + wsum[r]*tab[r*320 + 64 + c3];
        comb[n*192 + tid] = acc;
    }
}

// ---------------- K7b: agg GEMM + LN + relu, 4 nodes/block ----------------
__global__ __launch_bounds__(256) void k_agg(
    const float* __restrict__ comb, const float* __restrict__ wt,
    const float* __restrict__ agg_b,
    const float* __restrict__ g, const float* __restrict__ b, float* __restrict__ out)
{
    __shared__ float cb[4][192];
    __shared__ float red[8];
    int n0 = blockIdx.x*4, tid = threadIdx.x;
    for (int i = tid; i < 768; i += 256) cb[i/192][i%192] = comb[n0*192 + i];
    __syncthreads();
    int c = tid;
    float ab = agg_b[c];
    float acc[4] = {ab, ab, ab, ab};
    const float* aggT = wt + T_AGG;
    #pragma unroll 4
    for (int i = 0; i < 192; i++) {
        float w = aggT[i*256 + c];
        acc[0]=fmaf(cb[0][i],w,acc[0]); acc[1]=fmaf(cb[1][i],w,acc[1]);
        acc[2]=fmaf(cb[2][i],w,acc[2]); acc[3]=fmaf(cb[3][i],w,acc[3]);
    }
    int lane = c & 63, w_ = c >> 6;
    float gc = g[c], bc = b[c];
    #pragma unroll
    for (int j = 0; j < 4; j++) {
        float a = acc[j];
        float s = a;
        #pragma unroll
        for (int m = 32; m >= 1; m >>= 1) s += __shfl_xor(s, m, 64);
        if (lane == 0) red[w_] = s;
        __syncthreads();
        float mu = (red[0]+red[1]+red[2]+red[3]) * (1.f/256.f);
        float d = a - mu;
        float s2 = d*d;
        #pragma unroll
        for (int m = 32; m >= 1; m >>= 1) s2 += __shfl_xor(s2, m, 64);
        if (lane == 0) red[4+w_] = s2;
        __syncthreads();
        float var = (red[4]+red[5]+red[6]+red[7]) * (1.f/256.f);
        float y = d * rsqrtf(var + EPS) * gc + bc;
        out[(n0+j)*256 + c] = fmaxf(y, 0.f);
        __syncthreads();
    }
}

extern "C" void kernel_launch(void* const* d_in, const int* in_sizes, int n_in,
                              void* d_out, int out_size, void* d_ws, size_t ws_size,
                              hipStream_t stream)
{
    const float* x        = (const float*)d_in[0];
    const int*   eidx     = (const int*)d_in[1];
    const float* etime    = (const float*)d_in[2];
    const float* eattr    = (const float*)d_in[3];
    const float* te_w1    = (const float*)d_in[4];
    const float* te_b1    = (const float*)d_in[5];
    const float* te_w2    = (const float*)d_in[6];
    const float* te_b2    = (const float*)d_in[7];
    const float* te_ln_g  = (const float*)d_in[8];
    const float* te_ln_b  = (const float*)d_in[9];
    const float* inp_w    = (const float*)d_in[10];
    const float* inp_b    = (const float*)d_in[11];
    const float* wq       = (const float*)d_in[12];
    const float* bq       = (const float*)d_in[13];
    const float* wk       = (const float*)d_in[14];
    const float* bk       = (const float*)d_in[15];
    const float* wv       = (const float*)d_in[16];
    const float* bv       = (const float*)d_in[17];
    const float* aow      = (const float*)d_in[18];
    const float* aob      = (const float*)d_in[19];
    const float* ow       = (const float*)d_in[20];
    const float* ob       = (const float*)d_in[21];
    const float* sc_w1    = (const float*)d_in[22];
    const float* sc_b1    = (const float*)d_in[23];
    const float* sc_w2    = (const float*)d_in[24];
    const float* sc_b2    = (const float*)d_in[25];
    const float* agg_w    = (const float*)d_in[26];
    const float* agg_b    = (const float*)d_in[27];
    const float* agg_g    = (const float*)d_in[28];
    const float* agg_bb   = (const float*)d_in[29];
    const float* decay    = (const float*)d_in[30];
    float* ws = (float*)d_ws;
    float* out = (float*)d_out;
    ushort* qb   = (ushort*)(ws + O_QB);
    ushort* kbuf = (ushort*)(ws + O_KB);
    ushort* vt   = (ushort*)(ws + O_VT);
    float4* recS = (float4*)(ws + O_RECS);
    float2* recT = (float2*)(ws + O_RECT);
    int* slot_s  = (int*)(ws + O_SLS);
    float* wfS   = ws + O_WFS;
    int* cnt_s   = (int*)(ws + O_CNTS);
    int* cnt_t   = (int*)(ws + O_CNTT);
    float* nscore = ws + O_NSC;
    float* wtb   = ws + O_WT;
    float* comb  = ws + O_CMB;

    hipMemsetAsync(ws + O_CNTS, 0, 12288*sizeof(int), stream);

    k_tr<<<640, 256, 0, stream>>>(inp_w, wq, wk, wv, aow, ow, sc_w1, agg_w, wtb);
    k_setup<<<33, 64, 0, stream>>>(te_w1, te_b1, te_w2, te_b2, te_ln_g, te_ln_b,
                                   sc_w1, ws+O_TAB, ws+O_AUX);
    k_proj_qkv<<<N_NODES/4, 128, 0, stream>>>(x, wtb, inp_b, bq, bk, bv, qb, kbuf, vt);
    k_node_sc<<<N_NODES/4, 128, 0, stream>>>(x, wtb, ws+O_XSA, ws+O_XTB);
    k_fill<<<N_EDGES/256, 256, 0, stream>>>(eidx, eattr, cnt_s, cnt_t, slot_s, wfS, recT);
    k_edge<<<2048, 256, 0, stream>>>(eidx, etime, ws+O_TAB, ws+O_AUX,
                                     sc_b1, sc_w2, sc_b2, decay,
                                     ws+O_XSA, ws+O_XTB, slot_s, wfS,
                                     recS, nscore);
    k_attn<<<1024, 256, 0, stream>>>(qb, kbuf, vt, ws+O_CTXT);
    k_out_base<<<N_NODES/4, 128, 0, stream>>>(ws+O_CTXT, wtb, aob, ob, ws+O_BASE);
    k_gather<<<N_NODES, 256, 0, stream>>>(ws+O_BASE, recS, recT, cnt_s, cnt_t,
                                          nscore, ws+O_TAB, te_ln_b, comb);
    k_agg<<<N_NODES/4, 256, 0, stream>>>(comb, wtb, agg_b, agg_g, agg_bb, out);
}

// Round 7
// 248.097 us; speedup vs baseline: 4.8408x; 1.1032x over previous
//
#include <hip/hip_runtime.h>

#define N_NODES 4096
#define N_EDGES 262144
#define EPS 1e-5f
#define CAP 192

// workspace offsets (float units)
#define O_CTXT 0        // ctx^T f32 [128][4096]
#define O_BASE 524288   // base [4096][128]
#define O_XSA  1048576
#define O_XTB  1310720
#define O_TAB  1572864  // 33 regions x 320
#define O_AUX  1583424  // thr[32] + R0[64]
#define O_RECS 1583552  // float4 [4096][CAP]
#define O_RECT 4729280  // float2 [4096][CAP]
#define O_SLS  6302144  // int[E] slot in src list
#define O_WFS  6564288  // float[E] wf
#define O_CNTS 6826432
#define O_CNTT 6830528
#define O_NSC  6834624
#define O_QB   6838720  // bf16 [4][4096][32]
#define O_KB   7100864
#define O_VT   7363008  // bf16 [4][32][4096]
#define O_WT   7625152  // transposed weights
#define O_CMB  7788992  // comb [4096][192]
// within WT:
#define T_INP  0
#define T_WQ   16384
#define T_WK   32768
#define T_WV   49152
#define T_AW   65536
#define T_OW   81920
#define T_SC   98304
#define T_AGG  114688   // [192][256]

typedef __attribute__((ext_vector_type(8))) short short8v;
typedef __attribute__((ext_vector_type(4))) float f32x4;

__device__ __forceinline__ ushort f2bf(float x) {
    uint u = __builtin_bit_cast(uint, x);
    uint r = (u + 0x7FFFu + ((u >> 16) & 1u)) >> 16;
    return (ushort)r;
}
__device__ __forceinline__ float fexp2(float x) { return __builtin_amdgcn_exp2f(x); }

// ---------------- K-1: one-time weight transposes ----------------
__global__ __launch_bounds__(256) void k_tr(
    const float* __restrict__ inp_w, const float* __restrict__ wq,
    const float* __restrict__ wk, const float* __restrict__ wv,
    const float* __restrict__ aw, const float* __restrict__ ow,
    const float* __restrict__ sc_w1, const float* __restrict__ agg_w,
    float* __restrict__ wt)
{
    int idx = blockIdx.x*256 + threadIdx.x;
    if (idx < 114688) {
        int m = idx >> 14;
        int r = idx & 16383;
        int i = r >> 7, c = r & 127;
        float v;
        switch (m) {
            case 0: v = inp_w[c*128+i]; break;
            case 1: v = wq[c*128+i]; break;
            case 2: v = wk[c*128+i]; break;
            case 3: v = wv[c*128+i]; break;
            case 4: v = aw[c*128+i]; break;
            case 5: v = ow[c*128+i]; break;
            default: v = (c < 64) ? sc_w1[c*320+i] : sc_w1[(c-64)*320+128+i]; break;
        }
        wt[idx] = v;
    } else {
        int a = idx - 114688;
        int i = a >> 8, c = a & 255;
        wt[idx] = agg_w[c*192 + i];
    }
}

// ---------------- K0: region tables for piecewise-linear temporal MLP ----------------
__global__ __launch_bounds__(64) void k_setup(
    const float* __restrict__ te_w1, const float* __restrict__ te_b1,
    const float* __restrict__ te_w2, const float* __restrict__ te_b2,
    const float* __restrict__ ln_g, const float* __restrict__ ln_b,
    const float* __restrict__ sc_w1, float* __restrict__ tab, float* __restrict__ aux)
{
    __shared__ float t_s[32];
    __shared__ int pos_s[32];
    __shared__ float AG_s[64], BG_s[64];
    int r = blockIdx.x;
    int c = threadIdx.x;
    if (c < 32) {
        float w = te_w1[c], b = te_b1[c];
        t_s[c] = (w != 0.f) ? (-b / w) : 1e30f;
    }
    __syncthreads();
    if (c < 32) {
        float t = t_s[c];
        int p = 0;
        for (int i = 0; i < 32; i++) {
            float ti = t_s[i];
            p += (ti < t) || (ti == t && i < c);
        }
        pos_s[c] = p;
    }
    __syncthreads();
    float A = 0.f, B = te_b2[c];
    for (int j = 0; j < 32; j++) {
        float w = te_w1[j], b = te_b1[j];
        bool act = (w > 0.f) ? (pos_s[j] < r) : ((w < 0.f) ? (pos_s[j] >= r) : (b > 0.f));
        if (act) { float w2 = te_w2[c*32 + j]; A += w * w2; B += b * w2; }
    }
    float mA = A, mB = B;
    #pragma unroll
    for (int m = 32; m >= 1; m >>= 1) { mA += __shfl_xor(mA, m, 64); mB += __shfl_xor(mB, m, 64); }
    mA *= (1.f/64.f); mB *= (1.f/64.f);
    float a = A - mA, bq = B - mB;
    float qa = a*a, qb = a*bq, qc = bq*bq;
    #pragma unroll
    for (int m = 32; m >= 1; m >>= 1) {
        qa += __shfl_xor(qa, m, 64); qb += __shfl_xor(qb, m, 64); qc += __shfl_xor(qc, m, 64);
    }
    qa *= (1.f/64.f); qb *= (2.f/64.f); qc *= (1.f/64.f);
    float g = ln_g[c];
    float AG = a*g, BG = bq*g;
    AG_s[c] = AG; BG_s[c] = BG;
    float* row = tab + r*320;
    row[c] = AG; row[64+c] = BG;
    if (c == 0) { row[256] = qa; row[257] = qb; row[258] = qc; }
    __syncthreads();
    const float* wc = sc_w1 + c*320 + 256;
    float P = 0.f, Q = 0.f;
    for (int j = 0; j < 64; j++) { float w = wc[j]; P += AG_s[j]*w; Q += BG_s[j]*w; }
    row[128+c] = P; row[192+c] = Q;
    if (r == 0) {
        if (c < 32) aux[pos_s[c]] = t_s[c];
        float R0 = 0.f;
        for (int j = 0; j < 64; j++) R0 += ln_b[j] * wc[j];
        aux[32 + c] = R0;
    }
}

// ---------------- K1: projections + sc partials, 4 nodes/block ----------------
__global__ __launch_bounds__(128) void k_proj_qkv(
    const float* __restrict__ x, const float* __restrict__ wt,
    const float* __restrict__ inp_b,
    const float* __restrict__ bq, const float* __restrict__ bk, const float* __restrict__ bv,
    ushort* __restrict__ qb, ushort* __restrict__ kbuf, ushort* __restrict__ vt,
    float* __restrict__ xsa, float* __restrict__ xtb)
{
    __shared__ float xs[512];
    __shared__ float xps[4][128];
    int n0 = blockIdx.x*4;
    int c = threadIdx.x;
    for (int i = c; i < 512; i += 128) xs[i] = x[n0*128 + i];
    __syncthreads();
    const float* inpT = wt + T_INP;
    float ib = inp_b[c];
    float a0 = ib, a1 = ib, a2 = ib, a3 = ib;
    #pragma unroll 4
    for (int i = 0; i < 128; i++) {
        float w = inpT[i*128 + c];
        a0 = fmaf(xs[i], w, a0);
        a1 = fmaf(xs[128+i], w, a1);
        a2 = fmaf(xs[256+i], w, a2);
        a3 = fmaf(xs[384+i], w, a3);
    }
    xps[0][c] = a0; xps[1][c] = a1; xps[2][c] = a2; xps[3][c] = a3;
    // sc partials (uses xs, independent of xps sync)
    {
        const float* scT = wt + T_SC;
        float s0=0,s1=0,s2=0,s3=0;
        #pragma unroll 4
        for (int i = 0; i < 128; i++) {
            float w = scT[i*128 + c];
            s0=fmaf(xs[i],w,s0); s1=fmaf(xs[128+i],w,s1);
            s2=fmaf(xs[256+i],w,s2); s3=fmaf(xs[384+i],w,s3);
        }
        float sv[4] = {s0,s1,s2,s3};
        #pragma unroll
        for (int j = 0; j < 4; j++) {
            int n = n0 + j;
            if (c < 64) xsa[n*64+c] = sv[j]; else xtb[n*64+(c-64)] = sv[j];
        }
    }
    __syncthreads();
    float bqc = bq[c], bkc = bk[c], bvc = bv[c];
    float q0=bqc,q1=bqc,q2=bqc,q3=bqc;
    float k0=bkc,k1=bkc,k2=bkc,k3=bkc;
    float v0=bvc,v1=bvc,v2=bvc,v3=bvc;
    const float* wqT = wt + T_WQ;
    const float* wkT = wt + T_WK;
    const float* wvT = wt + T_WV;
    #pragma unroll 2
    for (int i = 0; i < 128; i++) {
        float wQ = wqT[i*128 + c], wK = wkT[i*128 + c], wV = wvT[i*128 + c];
        float x0 = xps[0][i], x1 = xps[1][i], x2 = xps[2][i], x3 = xps[3][i];
        q0=fmaf(x0,wQ,q0); q1=fmaf(x1,wQ,q1); q2=fmaf(x2,wQ,q2); q3=fmaf(x3,wQ,q3);
        k0=fmaf(x0,wK,k0); k1=fmaf(x1,wK,k1); k2=fmaf(x2,wK,k2); k3=fmaf(x3,wK,k3);
        v0=fmaf(x0,wV,v0); v1=fmaf(x1,wV,v1); v2=fmaf(x2,wV,v2); v3=fmaf(x3,wV,v3);
    }
    const float QSCALE = 0.17677669529663687f * 1.4426950408889634f;
    int h = c >> 5, d = c & 31;
    float qa_[4] = {q0,q1,q2,q3};
    float ka_[4] = {k0,k1,k2,k3};
    float va_[4] = {v0,v1,v2,v3};
    #pragma unroll
    for (int j = 0; j < 4; j++) {
        int n = n0 + j;
        int qi = h*131072 + n*32 + d;
        qb[qi]   = f2bf(qa_[j] * QSCALE);
        kbuf[qi] = f2bf(ka_[j]);
        vt[c*4096 + n] = f2bf(va_[j]);
    }
}

// ---------------- K2: MFMA flash attention (unchanged) ----------------
__global__ __launch_bounds__(256) void k_attn(
    const ushort* __restrict__ qb, const ushort* __restrict__ kb,
    const ushort* __restrict__ vt, float* __restrict__ ctxT)
{
    __shared__ float mbuf[4][16];
    __shared__ float lbuf[4][16];
    __shared__ float obuf[4][512];
    int tid = threadIdx.x;
    int lane = tid & 63;
    int wv = tid >> 6;
    int h = blockIdx.x & 3;
    int qt = blockIdx.x >> 2;
    int q15 = lane & 15;
    int g = lane >> 4;
    const ushort* qhb = qb + h*131072;
    const ushort* khb = kb + h*131072;
    const ushort* vhb = vt + h*131072;
    short8v qf = *(const short8v*)(qhb + (qt*16 + q15)*32 + g*8);
    int key0off = ((q15 >> 2) << 3) + (q15 & 3);
    f32x4 o0 = {0.f,0.f,0.f,0.f}, o1 = {0.f,0.f,0.f,0.f};
    const f32x4 z = {0.f,0.f,0.f,0.f};
    float m_run = -1e30f, l_run = 0.f;
    int kstart = wv * 1024;
    for (int k32 = kstart; k32 < kstart + 1024; k32 += 32) {
        short8v kf0 = *(const short8v*)(khb + (k32 + key0off)*32 + g*8);
        short8v kf1 = *(const short8v*)(khb + (k32 + key0off + 4)*32 + g*8);
        short8v vf0 = *(const short8v*)(vhb + q15*4096 + k32 + g*8);
        short8v vf1 = *(const short8v*)(vhb + (16 + q15)*4096 + k32 + g*8);
        f32x4 s0 = __builtin_amdgcn_mfma_f32_16x16x32_bf16(kf0, qf, z, 0, 0, 0);
        f32x4 s1 = __builtin_amdgcn_mfma_f32_16x16x32_bf16(kf1, qf, z, 0, 0, 0);
        float tmax = fmaxf(fmaxf(fmaxf(s0[0], s0[1]), fmaxf(s0[2], s0[3])),
                           fmaxf(fmaxf(s1[0], s1[1]), fmaxf(s1[2], s1[3])));
        tmax = fmaxf(tmax, __shfl_xor(tmax, 16, 64));
        tmax = fmaxf(tmax, __shfl_xor(tmax, 32, 64));
        float mnew = fmaxf(m_run, tmax);
        float sc = fexp2(m_run - mnew);
        float p0 = fexp2(s0[0] - mnew), p1 = fexp2(s0[1] - mnew);
        float p2 = fexp2(s0[2] - mnew), p3 = fexp2(s0[3] - mnew);
        float p4 = fexp2(s1[0] - mnew), p5 = fexp2(s1[1] - mnew);
        float p6 = fexp2(s1[2] - mnew), p7 = fexp2(s1[3] - mnew);
        float psum = ((p0 + p1) + (p2 + p3)) + ((p4 + p5) + (p6 + p7));
        psum += __shfl_xor(psum, 16, 64);
        psum += __shfl_xor(psum, 32, 64);
        l_run = l_run * sc + psum;
        m_run = mnew;
        #pragma unroll
        for (int r = 0; r < 4; r++) { o0[r] *= sc; o1[r] *= sc; }
        short8v pf;
        pf[0] = (short)f2bf(p0); pf[1] = (short)f2bf(p1);
        pf[2] = (short)f2bf(p2); pf[3] = (short)f2bf(p3);
        pf[4] = (short)f2bf(p4); pf[5] = (short)f2bf(p5);
        pf[6] = (short)f2bf(p6); pf[7] = (short)f2bf(p7);
        o0 = __builtin_amdgcn_mfma_f32_16x16x32_bf16(vf0, pf, o0, 0, 0, 0);
        o1 = __builtin_amdgcn_mfma_f32_16x16x32_bf16(vf1, pf, o1, 0, 0, 0);
    }
    if (lane < 16) { mbuf[wv][lane] = m_run; lbuf[wv][lane] = l_run; }
    #pragma unroll
    for (int r = 0; r < 4; r++) {
        obuf[wv][r*64 + lane]       = o0[r];
        obuf[wv][(4 + r)*64 + lane] = o1[r];
    }
    __syncthreads();
    for (int e = tid; e < 512; e += 256) {
        int lp = e & 63, r8 = e >> 6;
        int q = lp & 15;
        float m0 = mbuf[0][q], m1 = mbuf[1][q], m2 = mbuf[2][q], m3 = mbuf[3][q];
        float M = fmaxf(fmaxf(m0, m1), fmaxf(m2, m3));
        float sc0 = fexp2(m0 - M), sc1 = fexp2(m1 - M);
        float sc2 = fexp2(m2 - M), sc3 = fexp2(m3 - M);
        float L = lbuf[0][q]*sc0 + lbuf[1][q]*sc1 + lbuf[2][q]*sc2 + lbuf[3][q]*sc3;
        float a = obuf[0][e]*sc0 + obuf[1][e]*sc1 + obuf[2][e]*sc2 + obuf[3][e]*sc3;
        int d = ((lp >> 4) << 2) + (r8 & 3) + ((r8 >> 2) << 4);
        ctxT[(h*32 + d)*4096 + qt*16 + q] = a / L;
    }
}

// ---------------- K3: attn_out + outp, 4 nodes/block ----------------
__global__ __launch_bounds__(128) void k_out_base(
    const float* __restrict__ ctxT, const float* __restrict__ wt,
    const float* __restrict__ ab, const float* __restrict__ ob,
    float* __restrict__ base)
{
    __shared__ float cs[4][128];
    __shared__ float as[4][128];
    int n0 = blockIdx.x*4;
    int c = threadIdx.x;
    float4 cv = *(const float4*)(ctxT + c*4096 + n0);
    cs[0][c] = cv.x; cs[1][c] = cv.y; cs[2][c] = cv.z; cs[3][c] = cv.w;
    __syncthreads();
    float abc = ab[c];
    float a0=abc,a1=abc,a2=abc,a3=abc;
    const float* awT = wt + T_AW;
    #pragma unroll 4
    for (int i = 0; i < 128; i++) {
        float w = awT[i*128 + c];
        a0=fmaf(cs[0][i],w,a0); a1=fmaf(cs[1][i],w,a1);
        a2=fmaf(cs[2][i],w,a2); a3=fmaf(cs[3][i],w,a3);
    }
    as[0][c]=a0; as[1][c]=a1; as[2][c]=a2; as[3][c]=a3;
    __syncthreads();
    float obc = ob[c];
    float b0=obc,b1=obc,b2=obc,b3=obc;
    const float* owT = wt + T_OW;
    #pragma unroll 4
    for (int i = 0; i < 128; i++) {
        float w = owT[i*128 + c];
        b0=fmaf(as[0][i],w,b0); b1=fmaf(as[1][i],w,b1);
        b2=fmaf(as[2][i],w,b2); b3=fmaf(as[3][i],w,b3);
    }
    base[(n0+0)*128+c]=b0; base[(n0+1)*128+c]=b1;
    base[(n0+2)*128+c]=b2; base[(n0+3)*128+c]=b3;
}

// ---------------- K4: slots + eattr extraction + recT ----------------
__global__ __launch_bounds__(256) void k_fill(
    const int* __restrict__ eidx, const float* __restrict__ eattr,
    int* __restrict__ cnt_s, int* __restrict__ cnt_t,
    int* __restrict__ slot_s, float* __restrict__ wfS, float2* __restrict__ recT)
{
    int e = blockIdx.x*256 + threadIdx.x;
    int s = eidx[e], t = eidx[N_EDGES + e];
    float hier = eattr[e*17 + 16];
    float tfj  = eattr[e*17 + 5];
    float wf = 0.f, wr = 0.f;
    if (hier > 0.f) {
        wf = hier * (1.f/(1.f + __expf(-tfj))) * 0.3f;
        wr = hier * 0.1f;
    }
    slot_s[e] = atomicAdd(&cnt_s[s], 1);
    wfS[e] = wf;
    int pt = atomicAdd(&cnt_t[t], 1);
    if (pt < CAP)
        recT[t*CAP + pt] = make_float2(__builtin_bit_cast(float, (uint)s), wr);
}

// ---------------- K6: per-edge PWL, 16 lanes/edge, dual-ballot region ----------------
__global__ __launch_bounds__(256) void k_edge(
    const int* __restrict__ eidx, const float* __restrict__ etime,
    const float* __restrict__ tab, const float* __restrict__ aux,
    const float* __restrict__ sc_b1, const float* __restrict__ sc_w2,
    const float* __restrict__ sc_b2, const float* __restrict__ decay_p,
    const float* __restrict__ xsa, const float* __restrict__ xtb,
    const int* __restrict__ slot_s, const float* __restrict__ wfS,
    float4* __restrict__ recS, float* __restrict__ nscore)
{
    __shared__ float pq[33*128];    // [r][0..63]=P, [r][64..127]=Q
    __shared__ float qpoly[33*4];
    __shared__ float thrL[32];
    __shared__ float u0L[64];
    __shared__ float sw2L[64];
    int tid = threadIdx.x;
    for (int i = tid; i < 33*128; i += 256)
        pq[i] = tab[(i >> 7)*320 + 128 + (i & 127)];
    if (tid < 33) {
        qpoly[tid*4+0] = tab[tid*320+256];
        qpoly[tid*4+1] = tab[tid*320+257];
        qpoly[tid*4+2] = tab[tid*320+258];
    }
    if (tid < 32) thrL[tid] = aux[tid];
    if (tid < 64) { u0L[tid] = sc_b1[tid] + aux[32+tid]; sw2L[tid] = sc_w2[tid]; }
    __syncthreads();
    float decay = decay_p[0];
    float sb2 = sc_b2[0];
    int lane = tid & 63;
    int wv = tid >> 6;
    int g = lane >> 4, q = lane & 15;
    float th1 = thrL[q], th2 = thrL[16 + q];
    float4 u4 = *(const float4*)&u0L[q*4];
    float4 w4 = *(const float4*)&sw2L[q*4];
    // wave handles 8 edges per iteration (2 sets of 4); block covers 32
    for (int base_e = blockIdx.x*32; base_e < N_EDGES; base_e += 2048*32) {
        int eA = base_e + wv*8 + g;
        int eB = eA + 4;
        // --- load stage (independent) ---
        int srcA = eidx[eA], tgtA = eidx[N_EDGES + eA];
        int srcB = eidx[eB], tgtB = eidx[N_EDGES + eB];
        float tA = etime[eA], tB = etime[eB];
        float wtA = tA * __expf(-fabsf(tA)*decay);
        float wtB = tB * __expf(-fabsf(tB)*decay);
        // region via dual ballot (per-group popcount)
        unsigned long long bA1 = __ballot(wtA > th1);
        unsigned long long bA2 = __ballot(wtA > th2);
        unsigned long long bB1 = __ballot(wtB > th1);
        unsigned long long bB2 = __ballot(wtB > th2);
        int sh = g*16;
        int rA = __popc((uint)((bA1 >> sh) & 0xFFFF)) + __popc((uint)((bA2 >> sh) & 0xFFFF));
        int rB = __popc((uint)((bB1 >> sh) & 0xFFFF)) + __popc((uint)((bB2 >> sh) & 0xFFFF));
        // gathers (coalesced float4 per 16-lane group)
        float4 xaA = *(const float4*)&xsa[srcA*64 + q*4];
        float4 xbA = *(const float4*)&xtb[tgtA*64 + q*4];
        float4 xaB = *(const float4*)&xsa[srcB*64 + q*4];
        float4 xbB = *(const float4*)&xtb[tgtB*64 + q*4];
        float4 PA = *(const float4*)&pq[rA*128 + q*4];
        float4 QA = *(const float4*)&pq[rA*128 + 64 + q*4];
        float4 PB = *(const float4*)&pq[rB*128 + q*4];
        float4 QB = *(const float4*)&pq[rB*128 + 64 + q*4];
        float isdA = rsqrtf(fmaf(fmaf(qpoly[rA*4], wtA, qpoly[rA*4+1]), wtA, qpoly[rA*4+2]) + EPS);
        float isdB = rsqrtf(fmaf(fmaf(qpoly[rB*4], wtB, qpoly[rB*4+1]), wtB, qpoly[rB*4+2]) + EPS);
        float psA = 0.f, psB = 0.f;
        #pragma unroll
        for (int k = 0; k < 4; k++) {
            float rhA = fmaxf(fmaf(isdA, fmaf(((const float*)&PA)[k], wtA, ((const float*)&QA)[k]),
                              ((const float*)&u4)[k] + ((const float*)&xaA)[k] + ((const float*)&xbA)[k]), 0.f);
            float rhB = fmaxf(fmaf(isdB, fmaf(((const float*)&PB)[k], wtB, ((const float*)&QB)[k]),
                              ((const float*)&u4)[k] + ((const float*)&xaB)[k] + ((const float*)&xbB)[k]), 0.f);
            psA = fmaf(rhA, ((const float*)&w4)[k], psA);
            psB = fmaf(rhB, ((const float*)&w4)[k], psB);
        }
        #pragma unroll
        for (int m = 1; m <= 8; m <<= 1) {
            psA += __shfl_xor(psA, m, 64);
            psB += __shfl_xor(psB, m, 64);
        }
        float scoreA = 1.f / (1.f + __expf(-(psA + sb2)));
        float scoreB = 1.f / (1.f + __expf(-(psB + sb2)));
        if (q == 0) {
            atomicAdd(&nscore[srcA], scoreA);
            int slA = slot_s[eA];
            if (slA < CAP) {
                float4 rv;
                rv.x = __builtin_bit_cast(float, (uint)(tgtA | (rA << 12)));
                rv.y = wfS[eA];
                rv.z = scoreA * isdA * wtA;
                rv.w = scoreA * isdA;
                recS[srcA*CAP + slA] = rv;
            }
            atomicAdd(&nscore[srcB], scoreB);
            int slB = slot_s[eB];
            if (slB < CAP) {
                float4 rv;
                rv.x = __builtin_bit_cast(float, (uint)(tgtB | (rB << 12)));
                rv.y = wfS[eB];
                rv.z = scoreB * isdB * wtB;
                rv.w = scoreB * isdB;
                recS[srcB*CAP + slB] = rv;
            }
        }
    }
}

// ---------------- K7a: gather upd + nctx -> comb[n][192] ----------------
__global__ __launch_bounds__(256) void k_gather(
    const float* __restrict__ base, const float4* __restrict__ recS,
    const float2* __restrict__ recT, const int* __restrict__ cnt_s,
    const int* __restrict__ cnt_t, const float* __restrict__ nscore,
    const float* __restrict__ tab, const float* __restrict__ ln_b,
    float* __restrict__ comb)
{
    __shared__ int   sIdx[CAP];
    __shared__ float sWf[CAP], sZ[CAP], sWc[CAP];
    __shared__ int   tIdx[CAP];
    __shared__ float tWr[CAP];
    __shared__ float zsum[33], wsum[33];
    __shared__ float partial[2][128];
    int n = blockIdx.x, tid = threadIdx.x;
    int ns = min(cnt_s[n], CAP);
    int nt = min(cnt_t[n], CAP);
    int nsp = (ns + 15) & ~15;
    int ntp = (nt + 15) & ~15;
    const float4* rs = recS + n*CAP;
    const float2* rt = recT + n*CAP;
    if (tid < 33) { zsum[tid] = 0.f; wsum[tid] = 0.f; }
    for (int i = tid; i < nsp; i += 256) {
        if (i < ns) {
            float4 r = rs[i];
            sIdx[i] = (int)__builtin_bit_cast(uint, r.x);
            sWf[i] = r.y; sZ[i] = r.z; sWc[i] = r.w;
        } else { sIdx[i] = n; sWf[i] = 0.f; sZ[i] = 0.f; sWc[i] = 0.f; }
    }
    for (int i = tid; i < ntp; i += 256) {
        if (i < nt) {
            float2 r = rt[i];
            tIdx[i] = (int)__builtin_bit_cast(uint, r.x);
            tWr[i] = r.y;
        } else { tIdx[i] = n; tWr[i] = 0.f; }
    }
    __syncthreads();
    // per-region sums for nctx
    for (int i = tid; i < ns; i += 256) {
        int rg = (sIdx[i] >> 12) & 63;
        atomicAdd(&zsum[rg], sZ[i]);
        atomicAdd(&wsum[rg], sWc[i]);
    }
    // base-row gather, 2 halves, 8 loads in flight
    {
        int c = tid & 127, half = tid >> 7;
        float a0=0.f,a1=0.f,a2=0.f,a3=0.f,a4=0.f,a5=0.f,a6=0.f,a7=0.f;
        for (int i = half*8; i < nsp; i += 16) {
            a0 = fmaf(base[(sIdx[i+0] & 4095)*128 + c], sWf[i+0], a0);
            a1 = fmaf(base[(sIdx[i+1] & 4095)*128 + c], sWf[i+1], a1);
            a2 = fmaf(base[(sIdx[i+2] & 4095)*128 + c], sWf[i+2], a2);
            a3 = fmaf(base[(sIdx[i+3] & 4095)*128 + c], sWf[i+3], a3);
            a4 = fmaf(base[(sIdx[i+4] & 4095)*128 + c], sWf[i+4], a4);
            a5 = fmaf(base[(sIdx[i+5] & 4095)*128 + c], sWf[i+5], a5);
            a6 = fmaf(base[(sIdx[i+6] & 4095)*128 + c], sWf[i+6], a6);
            a7 = fmaf(base[(sIdx[i+7] & 4095)*128 + c], sWf[i+7], a7);
        }
        for (int i = half*8; i < ntp; i += 16) {
            a0 = fmaf(base[tIdx[i+0]*128 + c], tWr[i+0], a0);
            a1 = fmaf(base[tIdx[i+1]*128 + c], tWr[i+1], a1);
            a2 = fmaf(base[tIdx[i+2]*128 + c], tWr[i+2], a2);
            a3 = fmaf(base[tIdx[i+3]*128 + c], tWr[i+3], a3);
            a4 = fmaf(base[tIdx[i+4]*128 + c], tWr[i+4], a4);
            a5 = fmaf(base[tIdx[i+5]*128 + c], tWr[i+5], a5);
            a6 = fmaf(base[tIdx[i+6]*128 + c], tWr[i+6], a6);
            a7 = fmaf(base[tIdx[i+7]*128 + c], tWr[i+7], a7);
        }
        partial[half][c] = ((a0+a1)+(a2+a3)) + ((a4+a5)+(a6+a7));
    }
    __syncthreads();
    if (tid < 128) {
        comb[n*192 + tid] = base[n*128 + tid] + partial[0][tid] + partial[1][tid];
    } else if (tid < 192) {
        int c3 = tid - 128;
        float acc = nscore[n]*ln_b[c3];
        #pragma unroll
        for (int r = 0; r < 33; r++)
            acc += zsum[r]*tab[r*320 + c3] + wsum[r]*tab[r*320 + 64 + c3];
        comb[n*192 + tid] = acc;
    }
}

// ---------------- K7b: agg GEMM + LN + relu, 4 nodes/block ----------------
__global__ __launch_bounds__(256) void k_agg(
    const float* __restrict__ comb, const float* __restrict__ wt,
    const float* __restrict__ agg_b,
    const float* __restrict__ g, const float* __restrict__ b, float* __restrict__ out)
{
    __shared__ float cb[4][192];
    __shared__ float red[8];
    int n0 = blockIdx.x*4, tid = threadIdx.x;
    for (int i = tid; i < 768; i += 256) cb[i/192][i%192] = comb[n0*192 + i];
    __syncthreads();
    int c = tid;
    float ab = agg_b[c];
    float acc[4] = {ab, ab, ab, ab};
    const float* aggT = wt + T_AGG;
    #pragma unroll 4
    for (int i = 0; i < 192; i++) {
        float w = aggT[i*256 + c];
        acc[0]=fmaf(cb[0][i],w,acc[0]); acc[1]=fmaf(cb[1][i],w,acc[1]);
        acc[2]=fmaf(cb[2][i],w,acc[2]); acc[3]=fmaf(cb[3][i],w,acc[3]);
    }
    int lane = c & 63, w_ = c >> 6;
    float gc = g[c], bc = b[c];
    #pragma unroll
    for (int j = 0; j < 4; j++) {
        float a = acc[j];
        float s = a;
        #pragma unroll
        for (int m = 32; m >= 1; m >>= 1) s += __shfl_xor(s, m, 64);
        if (lane == 0) red[w_] = s;
        __syncthreads();
        float mu = (red[0]+red[1]+red[2]+red[3]) * (1.f/256.f);
        float d = a - mu;
        float s2 = d*d;
        #pragma unroll
        for (int m = 32; m >= 1; m >>= 1) s2 += __shfl_xor(s2, m, 64);
        if (lane == 0) red[4+w_] = s2;
        __syncthreads();
        float var = (red[4]+red[5]+red[6]+red[7]) * (1.f/256.f);
        float y = d * rsqrtf(var + EPS) * gc + bc;
        out[(n0+j)*256 + c] = fmaxf(y, 0.f);
        __syncthreads();
    }
}

extern "C" void kernel_launch(void* const* d_in, const int* in_sizes, int n_in,
                              void* d_out, int out_size, void* d_ws, size_t ws_size,
                              hipStream_t stream)
{
    const float* x        = (const float*)d_in[0];
    const int*   eidx     = (const int*)d_in[1];
    const float* etime    = (const float*)d_in[2];
    const float* eattr    = (const float*)d_in[3];
    const float* te_w1    = (const float*)d_in[4];
    const float* te_b1    = (const float*)d_in[5];
    const float* te_w2    = (const float*)d_in[6];
    const float* te_b2    = (const float*)d_in[7];
    const float* te_ln_g  = (const float*)d_in[8];
    const float* te_ln_b  = (const float*)d_in[9];
    const float* inp_w    = (const float*)d_in[10];
    const float* inp_b    = (const float*)d_in[11];
    const float* wq       = (const float*)d_in[12];
    const float* bq       = (const float*)d_in[13];
    const float* wk       = (const float*)d_in[14];
    const float* bk       = (const float*)d_in[15];
    const float* wv       = (const float*)d_in[16];
    const float* bv       = (const float*)d_in[17];
    const float* aow      = (const float*)d_in[18];
    const float* aob      = (const float*)d_in[19];
    const float* ow       = (const float*)d_in[20];
    const float* ob       = (const float*)d_in[21];
    const float* sc_w1    = (const float*)d_in[22];
    const float* sc_b1    = (const float*)d_in[23];
    const float* sc_w2    = (const float*)d_in[24];
    const float* sc_b2    = (const float*)d_in[25];
    const float* agg_w    = (const float*)d_in[26];
    const float* agg_b    = (const float*)d_in[27];
    const float* agg_g    = (const float*)d_in[28];
    const float* agg_bb   = (const float*)d_in[29];
    const float* decay    = (const float*)d_in[30];
    float* ws = (float*)d_ws;
    float* out = (float*)d_out;
    ushort* qb   = (ushort*)(ws + O_QB);
    ushort* kbuf = (ushort*)(ws + O_KB);
    ushort* vt   = (ushort*)(ws + O_VT);
    float4* recS = (float4*)(ws + O_RECS);
    float2* recT = (float2*)(ws + O_RECT);
    int* slot_s  = (int*)(ws + O_SLS);
    float* wfS   = ws + O_WFS;
    int* cnt_s   = (int*)(ws + O_CNTS);
    int* cnt_t   = (int*)(ws + O_CNTT);
    float* nscore = ws + O_NSC;
    float* wtb   = ws + O_WT;
    float* comb  = ws + O_CMB;

    hipMemsetAsync(ws + O_CNTS, 0, 12288*sizeof(int), stream);

    k_tr<<<640, 256, 0, stream>>>(inp_w, wq, wk, wv, aow, ow, sc_w1, agg_w, wtb);
    k_setup<<<33, 64, 0, stream>>>(te_w1, te_b1, te_w2, te_b2, te_ln_g, te_ln_b,
                                   sc_w1, ws+O_TAB, ws+O_AUX);
    k_proj_qkv<<<N_NODES/4, 128, 0, stream>>>(x, wtb, inp_b, bq, bk, bv, qb, kbuf, vt,
                                              ws+O_XSA, ws+O_XTB);
    k_fill<<<N_EDGES/256, 256, 0, stream>>>(eidx, eattr, cnt_s, cnt_t, slot_s, wfS, recT);
    k_edge<<<2048, 256, 0, stream>>>(eidx, etime, ws+O_TAB, ws+O_AUX,
                                     sc_b1, sc_w2, sc_b2, decay,
                                     ws+O_XSA, ws+O_XTB, slot_s, wfS,
                                     recS, nscore);
    k_attn<<<1024, 256, 0, stream>>>(qb, kbuf, vt, ws+O_CTXT);
    k_out_base<<<N_NODES/4, 128, 0, stream>>>(ws+O_CTXT, wtb, aob, ob, ws+O_BASE);
    k_gather<<<N_NODES, 256, 0, stream>>>(ws+O_BASE, recS, recT, cnt_s, cnt_t,
                                          nscore, ws+O_TAB, te_ln_b, comb);
    k_agg<<<N_NODES/4, 256, 0, stream>>>(comb, wtb, agg_b, agg_g, agg_bb, out);
}